// Round 1
// baseline (3791.236 us; speedup 1.0000x reference)
//
#include <hip/hip_runtime.h>

namespace {

constexpr int Bc   = 16;
constexpr int LQc  = 512;
constexpr int LKVc = 512;
constexpr int Dc   = 768;
constexpr int Hc   = 12;
constexpr int HDc  = 64;
constexpr int HIDc = 3072;

// ----------------------------------------------------------------------------
// LayerNorm: one block per row, 256 threads, D=768=3*256
// ----------------------------------------------------------------------------
__global__ __launch_bounds__(256) void ln_kernel(
    const float* __restrict__ X, const float* __restrict__ g,
    const float* __restrict__ bta, float* __restrict__ Y)
{
    const int row = blockIdx.x;
    const float* x = X + (size_t)row * Dc;
    float* y = Y + (size_t)row * Dc;
    const int t = threadIdx.x;
    const float v0 = x[t], v1 = x[t + 256], v2 = x[t + 512];
    float s  = v0 + v1 + v2;
    float ss = v0 * v0 + v1 * v1 + v2 * v2;
    #pragma unroll
    for (int off = 32; off > 0; off >>= 1) {
        s  += __shfl_down(s, off);
        ss += __shfl_down(ss, off);
    }
    __shared__ float red[8];
    __shared__ float mv[2];
    const int wid = t >> 6;
    if ((t & 63) == 0) { red[wid] = s; red[wid + 4] = ss; }
    __syncthreads();
    if (t == 0) {
        const float S  = red[0] + red[1] + red[2] + red[3];
        const float SS = red[4] + red[5] + red[6] + red[7];
        const float mean = S * (1.0f / Dc);
        const float var  = SS * (1.0f / Dc) - mean * mean;
        mv[0] = mean;
        mv[1] = rsqrtf(var + 1e-5f);
    }
    __syncthreads();
    const float mean = mv[0], inv = mv[1];
    y[t]       = (v0 - mean) * inv * g[t]       + bta[t];
    y[t + 256] = (v1 - mean) * inv * g[t + 256] + bta[t + 256];
    y[t + 512] = (v2 - mean) * inv * g[t + 512] + bta[t + 512];
}

// ----------------------------------------------------------------------------
// GEMM (NT): C[M,N] = A[M,K] @ W[N,K]^T (+bias) (+gelu) (+residual)
// 64x64 tile, BK=16, 256 threads, 4x4 per thread.
// M,N multiples of 64; K multiple of 16. All true for this problem.
// ----------------------------------------------------------------------------
__global__ __launch_bounds__(256) void gemm_nt(
    const float* __restrict__ A,
    const float* __restrict__ W,
    const float* __restrict__ bias,
    const float* __restrict__ resid,
    float* __restrict__ C,
    int M, int N, int K, int act)
{
    __shared__ __attribute__((aligned(16))) float As[16][68];
    __shared__ __attribute__((aligned(16))) float Ws[16][68];
    const int t  = threadIdx.x;
    const int tx = t & 15;
    const int ty = t >> 4;
    const int m0 = blockIdx.y << 6;
    const int n0 = blockIdx.x << 6;

    float acc[4][4] = {};

    const float* Aload = A + (size_t)(m0 + ty) * K + tx;
    const float* Wload = W + (size_t)(n0 + ty) * K + tx;

    for (int k0 = 0; k0 < K; k0 += 16) {
        #pragma unroll
        for (int p = 0; p < 4; ++p) {
            As[tx][ty + p * 16] = Aload[(size_t)(p * 16) * K + k0];
            Ws[tx][ty + p * 16] = Wload[(size_t)(p * 16) * K + k0];
        }
        __syncthreads();
        #pragma unroll
        for (int kk = 0; kk < 16; ++kk) {
            const float4 a4 = *(const float4*)&As[kk][ty * 4];
            const float4 b4 = *(const float4*)&Ws[kk][tx * 4];
            const float av[4] = {a4.x, a4.y, a4.z, a4.w};
            const float bv[4] = {b4.x, b4.y, b4.z, b4.w};
            #pragma unroll
            for (int i = 0; i < 4; ++i)
                #pragma unroll
                for (int j = 0; j < 4; ++j)
                    acc[i][j] = fmaf(av[i], bv[j], acc[i][j]);
        }
        __syncthreads();
    }

    const size_t mbase = (size_t)m0 + ty * 4;
    const int    nbase = n0 + tx * 4;
    #pragma unroll
    for (int i = 0; i < 4; ++i) {
        const size_t off = (mbase + i) * (size_t)N + nbase;
        float vv[4];
        #pragma unroll
        for (int j = 0; j < 4; ++j) {
            float v = acc[i][j];
            if (bias) v += bias[nbase + j];
            if (act)  v = 0.5f * v * (1.0f + erff(v * 0.70710678118654752f));
            vv[j] = v;
        }
        if (resid) {
            const float4 rs = *(const float4*)(resid + off);
            vv[0] += rs.x; vv[1] += rs.y; vv[2] += rs.z; vv[3] += rs.w;
        }
        float4 r; r.x = vv[0]; r.y = vv[1]; r.z = vv[2]; r.w = vv[3];
        *(float4*)(C + off) = r;
    }
}

// ----------------------------------------------------------------------------
// Attention: one block per (b, h, 16-q-row tile). 256 threads.
// Two-pass softmax; K staged through LDS; scores (16x512) in LDS;
// AV reads V from global (L2-resident), P via broadcast float4 LDS reads.
// ----------------------------------------------------------------------------
constexpr int QT = 16;
constexpr int KT = 64;
constexpr int PSS = 516;   // padded score stride (floats); 516*4B is 16B-mult

__global__ __launch_bounds__(256) void attn_kernel(
    const float* __restrict__ Qp, const float* __restrict__ Kp,
    const float* __restrict__ Vp, float* __restrict__ Op,
    int q_ts, int kv_ts, long long q_bs, long long kv_bs)
{
    __shared__ __attribute__((aligned(16))) float Ks[KT][68];
    __shared__ __attribute__((aligned(16))) float ps[QT][PSS];
    __shared__ float rowinv[QT];

    const int t = threadIdx.x;
    int bid = blockIdx.x;
    const int qt = bid & 31;          // LQ/QT = 32 tiles
    bid >>= 5;
    const int h = bid % Hc;
    const int b = bid / Hc;
    const int q0 = qt * QT;
    const float scale = 0.125f;       // HD^-0.5

    // my q row (q = t>>4) into registers: 64 floats
    const int myq = t >> 4;
    const float* qrow = Qp + (size_t)b * q_bs + (size_t)(q0 + myq) * q_ts + h * HDc;
    float4 qreg[16];
    #pragma unroll
    for (int i = 0; i < 16; ++i) qreg[i] = *(const float4*)(qrow + i * 4);

    const float* kbase = Kp + (size_t)b * kv_bs + h * HDc;

    // ---- scores: 16 q x 512 kv ----
    for (int kt = 0; kt < LKVc / KT; ++kt) {
        __syncthreads();   // protect Ks reuse across iterations
        #pragma unroll
        for (int p = 0; p < 4; ++p) {
            const int r = (t >> 4) + p * 16;
            const int c = (t & 15) * 4;
            *(float4*)&Ks[r][c] =
                *(const float4*)(kbase + (size_t)(kt * KT + r) * kv_ts + c);
        }
        __syncthreads();
        #pragma unroll
        for (int p = 0; p < 4; ++p) {
            const int kv = (t & 15) + p * 16;
            float s = 0.0f;
            #pragma unroll
            for (int d2 = 0; d2 < 16; ++d2) {
                const float4 k4 = *(const float4*)&Ks[kv][d2 * 4];
                s = fmaf(qreg[d2].x, k4.x, s);
                s = fmaf(qreg[d2].y, k4.y, s);
                s = fmaf(qreg[d2].z, k4.z, s);
                s = fmaf(qreg[d2].w, k4.w, s);
            }
            ps[myq][kt * KT + kv] = s * scale;
        }
    }
    __syncthreads();

    // ---- softmax: 16 lanes per row ----
    {
        const int row = t >> 4;
        const int l16 = t & 15;
        float m = -1e30f;
        #pragma unroll
        for (int i = 0; i < 32; ++i) m = fmaxf(m, ps[row][l16 + 16 * i]);
        #pragma unroll
        for (int off = 1; off < 16; off <<= 1) m = fmaxf(m, __shfl_xor(m, off));
        float ssum = 0.0f;
        #pragma unroll
        for (int i = 0; i < 32; ++i) {
            const int kv = l16 + 16 * i;
            const float e = expf(ps[row][kv] - m);
            ps[row][kv] = e;
            ssum += e;
        }
        #pragma unroll
        for (int off = 1; off < 16; off <<= 1) ssum += __shfl_xor(ssum, off);
        if (l16 == 0) rowinv[row] = 1.0f / ssum;
    }
    __syncthreads();

    // ---- AV: thread owns (d = t&63) for 4 q rows {qg, qg+4, qg+8, qg+12} ----
    const int d  = t & 63;
    const int qg = t >> 6;            // wave id: P reads are wave-uniform
    const float* vcol = Vp + (size_t)b * kv_bs + h * HDc + d;
    float acc0 = 0.f, acc1 = 0.f, acc2 = 0.f, acc3 = 0.f;
    for (int kv = 0; kv < LKVc; kv += 4) {
        const float v0 = vcol[(size_t)(kv + 0) * kv_ts];
        const float v1 = vcol[(size_t)(kv + 1) * kv_ts];
        const float v2 = vcol[(size_t)(kv + 2) * kv_ts];
        const float v3 = vcol[(size_t)(kv + 3) * kv_ts];
        const float4 p0 = *(const float4*)&ps[qg     ][kv];
        const float4 p1 = *(const float4*)&ps[qg +  4][kv];
        const float4 p2 = *(const float4*)&ps[qg +  8][kv];
        const float4 p3 = *(const float4*)&ps[qg + 12][kv];
        acc0 = fmaf(p0.x, v0, acc0); acc0 = fmaf(p0.y, v1, acc0);
        acc0 = fmaf(p0.z, v2, acc0); acc0 = fmaf(p0.w, v3, acc0);
        acc1 = fmaf(p1.x, v0, acc1); acc1 = fmaf(p1.y, v1, acc1);
        acc1 = fmaf(p1.z, v2, acc1); acc1 = fmaf(p1.w, v3, acc1);
        acc2 = fmaf(p2.x, v0, acc2); acc2 = fmaf(p2.y, v1, acc2);
        acc2 = fmaf(p2.z, v2, acc2); acc2 = fmaf(p2.w, v3, acc2);
        acc3 = fmaf(p3.x, v0, acc3); acc3 = fmaf(p3.y, v1, acc3);
        acc3 = fmaf(p3.z, v2, acc3); acc3 = fmaf(p3.w, v3, acc3);
    }
    const size_t obase = ((size_t)b * LQc + q0) * Dc + h * HDc + d;
    Op[obase + (size_t)(qg     ) * Dc] = acc0 * rowinv[qg     ];
    Op[obase + (size_t)(qg +  4) * Dc] = acc1 * rowinv[qg +  4];
    Op[obase + (size_t)(qg +  8) * Dc] = acc2 * rowinv[qg +  8];
    Op[obase + (size_t)(qg + 12) * Dc] = acc3 * rowinv[qg + 12];
}

} // anonymous namespace

// ----------------------------------------------------------------------------
// Launcher
// ----------------------------------------------------------------------------
extern "C" void kernel_launch(void* const* d_in, const int* in_sizes, int n_in,
                              void* d_out, int out_size, void* d_ws, size_t ws_size,
                              hipStream_t stream)
{
    const float* q_in   = (const float*)d_in[0];
    const float* kv_in  = (const float*)d_in[1];
    const float* n1g    = (const float*)d_in[2];
    const float* n1b    = (const float*)d_in[3];
    const float* qkv_w  = (const float*)d_in[4];
    const float* sa_w   = (const float*)d_in[5];
    const float* sa_b   = (const float*)d_in[6];
    const float* n2qg   = (const float*)d_in[7];
    const float* n2qb   = (const float*)d_in[8];
    const float* n2kg   = (const float*)d_in[9];
    const float* n2kb   = (const float*)d_in[10];
    const float* caq_w  = (const float*)d_in[11];
    const float* cakv_w = (const float*)d_in[12];
    const float* cap_w  = (const float*)d_in[13];
    const float* cap_b  = (const float*)d_in[14];
    const float* n3g    = (const float*)d_in[15];
    const float* n3b    = (const float*)d_in[16];
    const float* fc1_w  = (const float*)d_in[17];
    const float* fc1_b  = (const float*)d_in[18];
    const float* fc2_w  = (const float*)d_in[19];
    const float* fc2_b  = (const float*)d_in[20];
    float* out = (float*)d_out;

    const size_t MQ = (size_t)Bc * LQc * Dc;   // 6291456 floats
    float* ws      = (float*)d_ws;
    float* bufA    = ws;            // MQ   (x1 / xq / ca_out / x3)
    float* bufB    = ws + MQ;       // MQ   (sa_out / qc)
    float* bufC    = ws + 2 * MQ;   // MQ   (xkv)
    float* bufBig  = ws + 3 * MQ;   // 4MQ  (qkv -> kvc -> mlp hidden)

    const int ROWS = Bc * LQc;      // 8192
    const dim3 blk(256);
    const dim3 lnGrid(ROWS);
    const dim3 attnGrid(Bc * Hc * (LQc / QT));   // 6144

    // 1. x1 = LN1(q)
    ln_kernel<<<lnGrid, blk, 0, stream>>>(q_in, n1g, n1b, bufA);
    // 2. qkv = x1 @ qkv_w^T        (8192 x 2304)
    gemm_nt<<<dim3((3 * Dc) / 64, ROWS / 64), blk, 0, stream>>>(
        bufA, qkv_w, nullptr, nullptr, bufBig, ROWS, 3 * Dc, Dc, 0);
    // 3. sa_out = attend(q,k,v)    -> bufB
    attn_kernel<<<attnGrid, blk, 0, stream>>>(
        bufBig, bufBig + Dc, bufBig + 2 * Dc, bufB,
        3 * Dc, 3 * Dc, (long long)LQc * 3 * Dc, (long long)LKVc * 3 * Dc);
    // 4. q1 = sa_out @ sa_w^T + sa_b + q     -> out
    gemm_nt<<<dim3(Dc / 64, ROWS / 64), blk, 0, stream>>>(
        bufB, sa_w, sa_b, q_in, out, ROWS, Dc, Dc, 0);
    // 5. xq = LN2q(q1)             -> bufA
    ln_kernel<<<lnGrid, blk, 0, stream>>>(out, n2qg, n2qb, bufA);
    // 6. xkv = LN2kv(kv)           -> bufC
    ln_kernel<<<lnGrid, blk, 0, stream>>>(kv_in, n2kg, n2kb, bufC);
    // 7. qc = xq @ caq_w^T         -> bufB
    gemm_nt<<<dim3(Dc / 64, ROWS / 64), blk, 0, stream>>>(
        bufA, caq_w, nullptr, nullptr, bufB, ROWS, Dc, Dc, 0);
    // 8. kvc = xkv @ cakv_w^T      (8192 x 1536) -> bufBig
    gemm_nt<<<dim3((2 * Dc) / 64, ROWS / 64), blk, 0, stream>>>(
        bufC, cakv_w, nullptr, nullptr, bufBig, ROWS, 2 * Dc, Dc, 0);
    // 9. ca_out = attend(qc, kc, vc) -> bufA
    attn_kernel<<<attnGrid, blk, 0, stream>>>(
        bufB, bufBig, bufBig + Dc, bufA,
        Dc, 2 * Dc, (long long)LQc * Dc, (long long)LKVc * 2 * Dc);
    // 10. q2 = ca_out @ cap_w^T + cap_b + q1  -> out
    gemm_nt<<<dim3(Dc / 64, ROWS / 64), blk, 0, stream>>>(
        bufA, cap_w, cap_b, out, out, ROWS, Dc, Dc, 0);
    // 11. x3 = LN3(q2)             -> bufA
    ln_kernel<<<lnGrid, blk, 0, stream>>>(out, n3g, n3b, bufA);
    // 12. hmid = gelu(x3 @ fc1^T + fc1_b)     (8192 x 3072) -> bufBig
    gemm_nt<<<dim3(HIDc / 64, ROWS / 64), blk, 0, stream>>>(
        bufA, fc1_w, fc1_b, nullptr, bufBig, ROWS, HIDc, Dc, 1);
    // 13. out = hmid @ fc2^T + fc2_b + q2     -> out
    gemm_nt<<<dim3(Dc / 64, ROWS / 64), blk, 0, stream>>>(
        bufBig, fc2_w, fc2_b, out, out, ROWS, Dc, HIDc, 0);
}

// Round 2
// 2365.344 us; speedup vs baseline: 1.6028x; 1.6028x over previous
//
#include <hip/hip_runtime.h>

namespace {

constexpr int Bc   = 16;
constexpr int LQc  = 512;
constexpr int LKVc = 512;
constexpr int Dc   = 768;
constexpr int Hc   = 12;
constexpr int HDc  = 64;
constexpr int HIDc = 3072;

using bf16x8 = __attribute__((ext_vector_type(8))) short;
using f32x4  = __attribute__((ext_vector_type(4))) float;

__device__ inline short f2bf(float x) {
    union { float f; unsigned u; } v; v.f = x;
    const unsigned r = v.u + 0x7fffu + ((v.u >> 16) & 1u);
    return (short)(r >> 16);
}
__device__ inline float bf2f(short h) {
    union { unsigned u; float f; } v;
    v.u = ((unsigned)(unsigned short)h) << 16;
    return v.f;
}

// ----------------------------------------------------------------------------
// LayerNorm: one block per row, 256 threads, D=768=3*256
// ----------------------------------------------------------------------------
__global__ __launch_bounds__(256) void ln_kernel(
    const float* __restrict__ X, const float* __restrict__ g,
    const float* __restrict__ bta, float* __restrict__ Y)
{
    const int row = blockIdx.x;
    const float* x = X + (size_t)row * Dc;
    float* y = Y + (size_t)row * Dc;
    const int t = threadIdx.x;
    const float v0 = x[t], v1 = x[t + 256], v2 = x[t + 512];
    float s  = v0 + v1 + v2;
    float ss = v0 * v0 + v1 * v1 + v2 * v2;
    #pragma unroll
    for (int off = 32; off > 0; off >>= 1) {
        s  += __shfl_down(s, off);
        ss += __shfl_down(ss, off);
    }
    __shared__ float red[8];
    __shared__ float mv[2];
    const int wid = t >> 6;
    if ((t & 63) == 0) { red[wid] = s; red[wid + 4] = ss; }
    __syncthreads();
    if (t == 0) {
        const float S  = red[0] + red[1] + red[2] + red[3];
        const float SS = red[4] + red[5] + red[6] + red[7];
        const float mean = S * (1.0f / Dc);
        const float var  = SS * (1.0f / Dc) - mean * mean;
        mv[0] = mean;
        mv[1] = rsqrtf(var + 1e-5f);
    }
    __syncthreads();
    const float mean = mv[0], inv = mv[1];
    y[t]       = (v0 - mean) * inv * g[t]       + bta[t];
    y[t + 256] = (v1 - mean) * inv * g[t + 256] + bta[t + 256];
    y[t + 512] = (v2 - mean) * inv * g[t + 512] + bta[t + 512];
}

// ----------------------------------------------------------------------------
// MFMA GEMM (NT), bf16x3 split precision:
//   C[M,N] = A[M,K] @ W[N,K]^T (+bias) (+gelu) (+residual), fp32 in/out.
// Tile 128x128, BK=32, 256 threads = 4 waves in 2x2; each wave owns 64x64
// (4x4 fragments of 16x16x32). A,W are split on the fly into bf16 hi/lo;
// three MFMA passes (hh, lh, hl) accumulate in fp32.
// Requires M%128==0, N%128==0, K%32==0 (true for all calls here).
// ----------------------------------------------------------------------------
constexpr int LDSS = 40;   // padded LDS row stride in bf16 elems (80B: 8 bank-groups)

__global__ __launch_bounds__(256) void gemm_nt_mfma(
    const float* __restrict__ A,
    const float* __restrict__ W,
    const float* __restrict__ bias,
    const float* __restrict__ resid,
    float* __restrict__ C,
    int M, int N, int K, int act)
{
    __shared__ __attribute__((aligned(16))) short Ah[128 * LDSS];
    __shared__ __attribute__((aligned(16))) short Al[128 * LDSS];
    __shared__ __attribute__((aligned(16))) short Wh[128 * LDSS];
    __shared__ __attribute__((aligned(16))) short Wl[128 * LDSS];

    const int t    = threadIdx.x;
    const int lane = t & 63;
    const int wv   = t >> 6;
    const int wr   = wv >> 1;          // wave row (0..1)
    const int wc   = wv & 1;           // wave col (0..1)
    const int r16  = lane & 15;
    const int g4   = lane >> 4;        // 0..3
    const int m0   = blockIdx.y << 7;
    const int n0   = blockIdx.x << 7;

    // staging assignment: thread t loads 16 consecutive floats of row (t>>1),
    // cols (t&1)*16 .. +15, for both A and W tiles.
    const int srow = t >> 1;           // 0..127
    const int scol = (t & 1) << 4;     // 0 or 16
    const float* Ap = A + (size_t)(m0 + srow) * K + scol;
    const float* Wp = W + (size_t)(n0 + srow) * K + scol;
    const size_t sbase = (size_t)srow * LDSS + scol;

    f32x4 acc[4][4] = {};

    for (int k0 = 0; k0 < K; k0 += 32) {
        // ---- issue global loads early (overlap prior MFMA) ----
        float4 av[4], wv4[4];
        #pragma unroll
        for (int i = 0; i < 4; ++i) {
            av[i]  = *(const float4*)(Ap + k0 + i * 4);
            wv4[i] = *(const float4*)(Wp + k0 + i * 4);
        }
        __syncthreads();   // prior iter's frag reads done before overwrite

        // ---- split to bf16 hi/lo and stage to LDS ----
        bf16x8 ah0, ah1, al0, al1, wh0, wh1, wl0, wl1;
        #pragma unroll
        for (int i = 0; i < 4; ++i) {
            const float ax[4] = {av[i].x,  av[i].y,  av[i].z,  av[i].w};
            const float wx[4] = {wv4[i].x, wv4[i].y, wv4[i].z, wv4[i].w};
            #pragma unroll
            for (int j = 0; j < 4; ++j) {
                const int idx = i * 4 + j;
                const short ha = f2bf(ax[j]);
                const short la = f2bf(ax[j] - bf2f(ha));
                const short hw = f2bf(wx[j]);
                const short lw = f2bf(wx[j] - bf2f(hw));
                if (idx < 8) { ah0[idx] = ha; al0[idx] = la; wh0[idx] = hw; wl0[idx] = lw; }
                else { ah1[idx - 8] = ha; al1[idx - 8] = la; wh1[idx - 8] = hw; wl1[idx - 8] = lw; }
            }
        }
        *(bf16x8*)&Ah[sbase]     = ah0;  *(bf16x8*)&Ah[sbase + 8] = ah1;
        *(bf16x8*)&Al[sbase]     = al0;  *(bf16x8*)&Al[sbase + 8] = al1;
        *(bf16x8*)&Wh[sbase]     = wh0;  *(bf16x8*)&Wh[sbase + 8] = wh1;
        *(bf16x8*)&Wl[sbase]     = wl0;  *(bf16x8*)&Wl[sbase + 8] = wl1;
        __syncthreads();

        // ---- fragment reads ----
        bf16x8 fa_h[4], fa_l[4], fb_h[4], fb_l[4];
        #pragma unroll
        for (int f = 0; f < 4; ++f) {
            const int ar = (wr * 64 + f * 16 + r16) * LDSS + g4 * 8;
            const int br = (wc * 64 + f * 16 + r16) * LDSS + g4 * 8;
            fa_h[f] = *(const bf16x8*)&Ah[ar];
            fa_l[f] = *(const bf16x8*)&Al[ar];
            fb_h[f] = *(const bf16x8*)&Wh[br];
            fb_l[f] = *(const bf16x8*)&Wl[br];
        }

        // ---- 48 MFMA: hh + lh + hl ----
        #pragma unroll
        for (int i = 0; i < 4; ++i) {
            #pragma unroll
            for (int j = 0; j < 4; ++j) {
                acc[i][j] = __builtin_amdgcn_mfma_f32_16x16x32_bf16(
                    fa_h[i], fb_h[j], acc[i][j], 0, 0, 0);
                acc[i][j] = __builtin_amdgcn_mfma_f32_16x16x32_bf16(
                    fa_l[i], fb_h[j], acc[i][j], 0, 0, 0);
                acc[i][j] = __builtin_amdgcn_mfma_f32_16x16x32_bf16(
                    fa_h[i], fb_l[j], acc[i][j], 0, 0, 0);
            }
        }
    }

    // ---- epilogue: bias / gelu / residual, fp32 out ----
    #pragma unroll
    for (int i = 0; i < 4; ++i) {
        const int grow = m0 + wr * 64 + i * 16 + g4 * 4;
        #pragma unroll
        for (int j = 0; j < 4; ++j) {
            const int gcol = n0 + wc * 64 + j * 16 + r16;
            const float bv = bias ? bias[gcol] : 0.0f;
            #pragma unroll
            for (int r = 0; r < 4; ++r) {
                float v = acc[i][j][r] + bv;
                if (act) v = 0.5f * v * (1.0f + erff(v * 0.70710678118654752f));
                if (resid) v += resid[(size_t)(grow + r) * N + gcol];
                C[(size_t)(grow + r) * N + gcol] = v;
            }
        }
    }
}

// ----------------------------------------------------------------------------
// Attention: one block per (b, h, 16-q-row tile). 256 threads. (unchanged)
// ----------------------------------------------------------------------------
constexpr int QT = 16;
constexpr int KT = 64;
constexpr int PSS = 516;

__global__ __launch_bounds__(256) void attn_kernel(
    const float* __restrict__ Qp, const float* __restrict__ Kp,
    const float* __restrict__ Vp, float* __restrict__ Op,
    int q_ts, int kv_ts, long long q_bs, long long kv_bs)
{
    __shared__ __attribute__((aligned(16))) float Ks[KT][68];
    __shared__ __attribute__((aligned(16))) float ps[QT][PSS];
    __shared__ float rowinv[QT];

    const int t = threadIdx.x;
    int bid = blockIdx.x;
    const int qt = bid & 31;
    bid >>= 5;
    const int h = bid % Hc;
    const int b = bid / Hc;
    const int q0 = qt * QT;
    const float scale = 0.125f;

    const int myq = t >> 4;
    const float* qrow = Qp + (size_t)b * q_bs + (size_t)(q0 + myq) * q_ts + h * HDc;
    float4 qreg[16];
    #pragma unroll
    for (int i = 0; i < 16; ++i) qreg[i] = *(const float4*)(qrow + i * 4);

    const float* kbase = Kp + (size_t)b * kv_bs + h * HDc;

    for (int kt = 0; kt < LKVc / KT; ++kt) {
        __syncthreads();
        #pragma unroll
        for (int p = 0; p < 4; ++p) {
            const int r = (t >> 4) + p * 16;
            const int c = (t & 15) * 4;
            *(float4*)&Ks[r][c] =
                *(const float4*)(kbase + (size_t)(kt * KT + r) * kv_ts + c);
        }
        __syncthreads();
        #pragma unroll
        for (int p = 0; p < 4; ++p) {
            const int kv = (t & 15) + p * 16;
            float s = 0.0f;
            #pragma unroll
            for (int d2 = 0; d2 < 16; ++d2) {
                const float4 k4 = *(const float4*)&Ks[kv][d2 * 4];
                s = fmaf(qreg[d2].x, k4.x, s);
                s = fmaf(qreg[d2].y, k4.y, s);
                s = fmaf(qreg[d2].z, k4.z, s);
                s = fmaf(qreg[d2].w, k4.w, s);
            }
            ps[myq][kt * KT + kv] = s * scale;
        }
    }
    __syncthreads();

    {
        const int row = t >> 4;
        const int l16 = t & 15;
        float m = -1e30f;
        #pragma unroll
        for (int i = 0; i < 32; ++i) m = fmaxf(m, ps[row][l16 + 16 * i]);
        #pragma unroll
        for (int off = 1; off < 16; off <<= 1) m = fmaxf(m, __shfl_xor(m, off));
        float ssum = 0.0f;
        #pragma unroll
        for (int i = 0; i < 32; ++i) {
            const int kv = l16 + 16 * i;
            const float e = expf(ps[row][kv] - m);
            ps[row][kv] = e;
            ssum += e;
        }
        #pragma unroll
        for (int off = 1; off < 16; off <<= 1) ssum += __shfl_xor(ssum, off);
        if (l16 == 0) rowinv[row] = 1.0f / ssum;
    }
    __syncthreads();

    const int d  = t & 63;
    const int qg = t >> 6;
    const float* vcol = Vp + (size_t)b * kv_bs + h * HDc + d;
    float acc0 = 0.f, acc1 = 0.f, acc2 = 0.f, acc3 = 0.f;
    for (int kv = 0; kv < LKVc; kv += 4) {
        const float v0 = vcol[(size_t)(kv + 0) * kv_ts];
        const float v1 = vcol[(size_t)(kv + 1) * kv_ts];
        const float v2 = vcol[(size_t)(kv + 2) * kv_ts];
        const float v3 = vcol[(size_t)(kv + 3) * kv_ts];
        const float4 p0 = *(const float4*)&ps[qg     ][kv];
        const float4 p1 = *(const float4*)&ps[qg +  4][kv];
        const float4 p2 = *(const float4*)&ps[qg +  8][kv];
        const float4 p3 = *(const float4*)&ps[qg + 12][kv];
        acc0 = fmaf(p0.x, v0, acc0); acc0 = fmaf(p0.y, v1, acc0);
        acc0 = fmaf(p0.z, v2, acc0); acc0 = fmaf(p0.w, v3, acc0);
        acc1 = fmaf(p1.x, v0, acc1); acc1 = fmaf(p1.y, v1, acc1);
        acc1 = fmaf(p1.z, v2, acc1); acc1 = fmaf(p1.w, v3, acc1);
        acc2 = fmaf(p2.x, v0, acc2); acc2 = fmaf(p2.y, v1, acc2);
        acc2 = fmaf(p2.z, v2, acc2); acc2 = fmaf(p2.w, v3, acc2);
        acc3 = fmaf(p3.x, v0, acc3); acc3 = fmaf(p3.y, v1, acc3);
        acc3 = fmaf(p3.z, v2, acc3); acc3 = fmaf(p3.w, v3, acc3);
    }
    const size_t obase = ((size_t)b * LQc + q0) * Dc + h * HDc + d;
    Op[obase + (size_t)(qg     ) * Dc] = acc0 * rowinv[qg     ];
    Op[obase + (size_t)(qg +  4) * Dc] = acc1 * rowinv[qg +  4];
    Op[obase + (size_t)(qg +  8) * Dc] = acc2 * rowinv[qg +  8];
    Op[obase + (size_t)(qg + 12) * Dc] = acc3 * rowinv[qg + 12];
}

} // anonymous namespace

// ----------------------------------------------------------------------------
// Launcher
// ----------------------------------------------------------------------------
extern "C" void kernel_launch(void* const* d_in, const int* in_sizes, int n_in,
                              void* d_out, int out_size, void* d_ws, size_t ws_size,
                              hipStream_t stream)
{
    const float* q_in   = (const float*)d_in[0];
    const float* kv_in  = (const float*)d_in[1];
    const float* n1g    = (const float*)d_in[2];
    const float* n1b    = (const float*)d_in[3];
    const float* qkv_w  = (const float*)d_in[4];
    const float* sa_w   = (const float*)d_in[5];
    const float* sa_b   = (const float*)d_in[6];
    const float* n2qg   = (const float*)d_in[7];
    const float* n2qb   = (const float*)d_in[8];
    const float* n2kg   = (const float*)d_in[9];
    const float* n2kb   = (const float*)d_in[10];
    const float* caq_w  = (const float*)d_in[11];
    const float* cakv_w = (const float*)d_in[12];
    const float* cap_w  = (const float*)d_in[13];
    const float* cap_b  = (const float*)d_in[14];
    const float* n3g    = (const float*)d_in[15];
    const float* n3b    = (const float*)d_in[16];
    const float* fc1_w  = (const float*)d_in[17];
    const float* fc1_b  = (const float*)d_in[18];
    const float* fc2_w  = (const float*)d_in[19];
    const float* fc2_b  = (const float*)d_in[20];
    float* out = (float*)d_out;

    const size_t MQ = (size_t)Bc * LQc * Dc;   // 6291456 floats
    float* ws      = (float*)d_ws;
    float* bufA    = ws;            // MQ   (x1 / xq / ca_out / x3)
    float* bufB    = ws + MQ;       // MQ   (sa_out / qc)
    float* bufC    = ws + 2 * MQ;   // MQ   (xkv)
    float* bufBig  = ws + 3 * MQ;   // 4MQ  (qkv -> kvc -> mlp hidden)

    const int ROWS = Bc * LQc;      // 8192
    const dim3 blk(256);
    const dim3 lnGrid(ROWS);
    const dim3 attnGrid(Bc * Hc * (LQc / QT));   // 6144

    // 1. x1 = LN1(q)
    ln_kernel<<<lnGrid, blk, 0, stream>>>(q_in, n1g, n1b, bufA);
    // 2. qkv = x1 @ qkv_w^T        (8192 x 2304)
    gemm_nt_mfma<<<dim3((3 * Dc) / 128, ROWS / 128), blk, 0, stream>>>(
        bufA, qkv_w, nullptr, nullptr, bufBig, ROWS, 3 * Dc, Dc, 0);
    // 3. sa_out = attend(q,k,v)    -> bufB
    attn_kernel<<<attnGrid, blk, 0, stream>>>(
        bufBig, bufBig + Dc, bufBig + 2 * Dc, bufB,
        3 * Dc, 3 * Dc, (long long)LQc * 3 * Dc, (long long)LKVc * 3 * Dc);
    // 4. q1 = sa_out @ sa_w^T + sa_b + q     -> out
    gemm_nt_mfma<<<dim3(Dc / 128, ROWS / 128), blk, 0, stream>>>(
        bufB, sa_w, sa_b, q_in, out, ROWS, Dc, Dc, 0);
    // 5. xq = LN2q(q1)             -> bufA
    ln_kernel<<<lnGrid, blk, 0, stream>>>(out, n2qg, n2qb, bufA);
    // 6. xkv = LN2kv(kv)           -> bufC
    ln_kernel<<<lnGrid, blk, 0, stream>>>(kv_in, n2kg, n2kb, bufC);
    // 7. qc = xq @ caq_w^T         -> bufB
    gemm_nt_mfma<<<dim3(Dc / 128, ROWS / 128), blk, 0, stream>>>(
        bufA, caq_w, nullptr, nullptr, bufB, ROWS, Dc, Dc, 0);
    // 8. kvc = xkv @ cakv_w^T      (8192 x 1536) -> bufBig
    gemm_nt_mfma<<<dim3((2 * Dc) / 128, ROWS / 128), blk, 0, stream>>>(
        bufC, cakv_w, nullptr, nullptr, bufBig, ROWS, 2 * Dc, Dc, 0);
    // 9. ca_out = attend(qc, kc, vc) -> bufA
    attn_kernel<<<attnGrid, blk, 0, stream>>>(
        bufB, bufBig, bufBig + Dc, bufA,
        Dc, 2 * Dc, (long long)LQc * Dc, (long long)LKVc * 2 * Dc);
    // 10. q2 = ca_out @ cap_w^T + cap_b + q1  -> out
    gemm_nt_mfma<<<dim3(Dc / 128, ROWS / 128), blk, 0, stream>>>(
        bufA, cap_w, cap_b, out, out, ROWS, Dc, Dc, 0);
    // 11. x3 = LN3(q2)             -> bufA
    ln_kernel<<<lnGrid, blk, 0, stream>>>(out, n3g, n3b, bufA);
    // 12. hmid = gelu(x3 @ fc1^T + fc1_b)     (8192 x 3072) -> bufBig
    gemm_nt_mfma<<<dim3(HIDc / 128, ROWS / 128), blk, 0, stream>>>(
        bufA, fc1_w, fc1_b, nullptr, bufBig, ROWS, HIDc, Dc, 1);
    // 13. out = hmid @ fc2^T + fc2_b + q2     -> out
    gemm_nt_mfma<<<dim3(Dc / 128, ROWS / 128), blk, 0, stream>>>(
        bufBig, fc2_w, fc2_b, out, out, ROWS, Dc, HIDc, 0);
}

// Round 3
// 1184.380 us; speedup vs baseline: 3.2010x; 1.9971x over previous
//
#include <hip/hip_runtime.h>

namespace {

constexpr int Bc   = 16;
constexpr int LQc  = 512;
constexpr int LKVc = 512;
constexpr int Dc   = 768;
constexpr int Hc   = 12;
constexpr int HDc  = 64;
constexpr int HIDc = 3072;

using bf16x8 = __attribute__((ext_vector_type(8))) short;
using short4v = __attribute__((ext_vector_type(4))) short;
using f32x4  = __attribute__((ext_vector_type(4))) float;

__device__ inline short f2bf(float x) {              // round-to-nearest-even
    union { float f; unsigned u; } v; v.f = x;
    const unsigned r = v.u + 0x7fffu + ((v.u >> 16) & 1u);
    return (short)(r >> 16);
}
__device__ inline float bf2f(short h) {
    union { unsigned u; float f; } v;
    v.u = ((unsigned)(unsigned short)h) << 16;
    return v.f;
}
__device__ inline short bhi(float x) {               // truncating bf16 split (hi)
    union { float f; unsigned u; } v; v.f = x;
    return (short)(v.u >> 16);
}
__device__ inline float bresid(float x, short hi) {  // exact residual x - hi
    return x - bf2f(hi);
}

// ----------------------------------------------------------------------------
// LayerNorm: one block per row, 256 threads, D=768=3*256  (unchanged)
// ----------------------------------------------------------------------------
__global__ __launch_bounds__(256) void ln_kernel(
    const float* __restrict__ X, const float* __restrict__ g,
    const float* __restrict__ bta, float* __restrict__ Y)
{
    const int row = blockIdx.x;
    const float* x = X + (size_t)row * Dc;
    float* y = Y + (size_t)row * Dc;
    const int t = threadIdx.x;
    const float v0 = x[t], v1 = x[t + 256], v2 = x[t + 512];
    float s  = v0 + v1 + v2;
    float ss = v0 * v0 + v1 * v1 + v2 * v2;
    #pragma unroll
    for (int off = 32; off > 0; off >>= 1) {
        s  += __shfl_down(s, off);
        ss += __shfl_down(ss, off);
    }
    __shared__ float red[8];
    __shared__ float mv[2];
    const int wid = t >> 6;
    if ((t & 63) == 0) { red[wid] = s; red[wid + 4] = ss; }
    __syncthreads();
    if (t == 0) {
        const float S  = red[0] + red[1] + red[2] + red[3];
        const float SS = red[4] + red[5] + red[6] + red[7];
        const float mean = S * (1.0f / Dc);
        const float var  = SS * (1.0f / Dc) - mean * mean;
        mv[0] = mean;
        mv[1] = rsqrtf(var + 1e-5f);
    }
    __syncthreads();
    const float mean = mv[0], inv = mv[1];
    y[t]       = (v0 - mean) * inv * g[t]       + bta[t];
    y[t + 256] = (v1 - mean) * inv * g[t + 256] + bta[t + 256];
    y[t + 512] = (v2 - mean) * inv * g[t + 512] + bta[t + 512];
}

// ----------------------------------------------------------------------------
// MFMA GEMM (NT), bf16x3 split precision  (unchanged from round 2)
// ----------------------------------------------------------------------------
constexpr int LDSS = 40;

__global__ __launch_bounds__(256) void gemm_nt_mfma(
    const float* __restrict__ A,
    const float* __restrict__ W,
    const float* __restrict__ bias,
    const float* __restrict__ resid,
    float* __restrict__ C,
    int M, int N, int K, int act)
{
    __shared__ __attribute__((aligned(16))) short Ah[128 * LDSS];
    __shared__ __attribute__((aligned(16))) short Al[128 * LDSS];
    __shared__ __attribute__((aligned(16))) short Wh[128 * LDSS];
    __shared__ __attribute__((aligned(16))) short Wl[128 * LDSS];

    const int t    = threadIdx.x;
    const int lane = t & 63;
    const int wv   = t >> 6;
    const int wr   = wv >> 1;
    const int wc   = wv & 1;
    const int r16  = lane & 15;
    const int g4   = lane >> 4;
    const int m0   = blockIdx.y << 7;
    const int n0   = blockIdx.x << 7;

    const int srow = t >> 1;
    const int scol = (t & 1) << 4;
    const float* Ap = A + (size_t)(m0 + srow) * K + scol;
    const float* Wp = W + (size_t)(n0 + srow) * K + scol;
    const size_t sbase = (size_t)srow * LDSS + scol;

    f32x4 acc[4][4] = {};

    for (int k0 = 0; k0 < K; k0 += 32) {
        float4 av[4], wv4[4];
        #pragma unroll
        for (int i = 0; i < 4; ++i) {
            av[i]  = *(const float4*)(Ap + k0 + i * 4);
            wv4[i] = *(const float4*)(Wp + k0 + i * 4);
        }
        __syncthreads();

        bf16x8 ah0, ah1, al0, al1, wh0, wh1, wl0, wl1;
        #pragma unroll
        for (int i = 0; i < 4; ++i) {
            const float ax[4] = {av[i].x,  av[i].y,  av[i].z,  av[i].w};
            const float wx[4] = {wv4[i].x, wv4[i].y, wv4[i].z, wv4[i].w};
            #pragma unroll
            for (int j = 0; j < 4; ++j) {
                const int idx = i * 4 + j;
                const short ha = f2bf(ax[j]);
                const short la = f2bf(ax[j] - bf2f(ha));
                const short hw = f2bf(wx[j]);
                const short lw = f2bf(wx[j] - bf2f(hw));
                if (idx < 8) { ah0[idx] = ha; al0[idx] = la; wh0[idx] = hw; wl0[idx] = lw; }
                else { ah1[idx - 8] = ha; al1[idx - 8] = la; wh1[idx - 8] = hw; wl1[idx - 8] = lw; }
            }
        }
        *(bf16x8*)&Ah[sbase]     = ah0;  *(bf16x8*)&Ah[sbase + 8] = ah1;
        *(bf16x8*)&Al[sbase]     = al0;  *(bf16x8*)&Al[sbase + 8] = al1;
        *(bf16x8*)&Wh[sbase]     = wh0;  *(bf16x8*)&Wh[sbase + 8] = wh1;
        *(bf16x8*)&Wl[sbase]     = wl0;  *(bf16x8*)&Wl[sbase + 8] = wl1;
        __syncthreads();

        bf16x8 fa_h[4], fa_l[4], fb_h[4], fb_l[4];
        #pragma unroll
        for (int f = 0; f < 4; ++f) {
            const int ar = (wr * 64 + f * 16 + r16) * LDSS + g4 * 8;
            const int br = (wc * 64 + f * 16 + r16) * LDSS + g4 * 8;
            fa_h[f] = *(const bf16x8*)&Ah[ar];
            fa_l[f] = *(const bf16x8*)&Al[ar];
            fb_h[f] = *(const bf16x8*)&Wh[br];
            fb_l[f] = *(const bf16x8*)&Wl[br];
        }

        #pragma unroll
        for (int i = 0; i < 4; ++i) {
            #pragma unroll
            for (int j = 0; j < 4; ++j) {
                acc[i][j] = __builtin_amdgcn_mfma_f32_16x16x32_bf16(
                    fa_h[i], fb_h[j], acc[i][j], 0, 0, 0);
                acc[i][j] = __builtin_amdgcn_mfma_f32_16x16x32_bf16(
                    fa_l[i], fb_h[j], acc[i][j], 0, 0, 0);
                acc[i][j] = __builtin_amdgcn_mfma_f32_16x16x32_bf16(
                    fa_h[i], fb_l[j], acc[i][j], 0, 0, 0);
            }
        }
    }

    #pragma unroll
    for (int i = 0; i < 4; ++i) {
        const int grow = m0 + wr * 64 + i * 16 + g4 * 4;
        #pragma unroll
        for (int j = 0; j < 4; ++j) {
            const int gcol = n0 + wc * 64 + j * 16 + r16;
            const float bv = bias ? bias[gcol] : 0.0f;
            #pragma unroll
            for (int r = 0; r < 4; ++r) {
                float v = acc[i][j][r] + bv;
                if (act) v = 0.5f * v * (1.0f + erff(v * 0.70710678118654752f));
                if (resid) v += resid[(size_t)(grow + r) * N + gcol];
                C[(size_t)(grow + r) * N + gcol] = v;
            }
        }
    }
}

// ----------------------------------------------------------------------------
// MFMA flash attention. Block = 256 thr (4 waves), 64 q rows per block.
// Swapped QK^T (S^T = K*Q^T) -> lane-local softmax; online (flash) rescale;
// P through LDS tiles; V transpose-staged; all via 16x16x32 bf16 MFMA with
// hi/lo split (3-term) for QK and PV. XOR-swizzled LDS rows.
// ----------------------------------------------------------------------------
__global__ __launch_bounds__(256) void attn_mfma(
    const float* __restrict__ Qp, const float* __restrict__ Kp,
    const float* __restrict__ Vp, float* __restrict__ Op,
    int q_ts, int kv_ts, long long q_bs, long long kv_bs)
{
    __shared__ __attribute__((aligned(16))) short Kth[64 * 64];
    __shared__ __attribute__((aligned(16))) short Ktl[64 * 64];
    __shared__ __attribute__((aligned(16))) short Vth[64 * 64];
    __shared__ __attribute__((aligned(16))) short Vtl[64 * 64];
    __shared__ __attribute__((aligned(16))) short Pth[64 * 64];
    __shared__ __attribute__((aligned(16))) short Ptl[64 * 64];

    const int t    = threadIdx.x;
    const int lane = t & 63;
    const int w    = t >> 6;           // wave 0..3 -> q rows w*16..w*16+15
    const int r16  = lane & 15;
    const int g4   = lane >> 4;

    int bid = blockIdx.x;
    const int qt = bid & 7;  bid >>= 3;      // LQ/64 = 8 q-tiles
    const int h  = bid % Hc;
    const int b  = bid / Hc;
    const int q0 = qt * 64;

    const float* qbase = Qp + (size_t)b * q_bs + h * HDc;
    const float* kbase = Kp + (size_t)b * kv_bs + h * HDc;
    const float* vbase = Vp + (size_t)b * kv_bs + h * HDc;

    const int myq = w * 16 + r16;            // local q row 0..63
    const int qsw = (myq & 7) << 3;

    // ---- Q fragments (B-operand), pre-scaled into exp2 domain ----
    const float qscale = 0.125f * 1.44269504088896340736f;   // hd^-0.5 * log2(e)
    bf16x8 qh[2], ql[2];
    {
        const float* qrow = qbase + (size_t)(q0 + myq) * q_ts;
        #pragma unroll
        for (int ks = 0; ks < 2; ++ks) {
            const f32x4 u0 = *(const f32x4*)(qrow + ks * 32 + g4 * 8);
            const f32x4 u1 = *(const f32x4*)(qrow + ks * 32 + g4 * 8 + 4);
            #pragma unroll
            for (int j = 0; j < 4; ++j) {
                float x0 = u0[j] * qscale;
                float x1 = u1[j] * qscale;
                const short h0 = bhi(x0), h1 = bhi(x1);
                qh[ks][j]     = h0;  qh[ks][j + 4] = h1;
                ql[ks][j]     = bhi(bresid(x0, h0));
                ql[ks][j + 4] = bhi(bresid(x1, h1));
            }
        }
    }

    // staging indices
    const int skv = t >> 2,         sd = (t & 3) * 16;      // K staging
    const int vkv = (t >> 4) * 4,   vd = (t & 15) * 4;      // V staging
    const int ksw = (skv & 7) << 3;

    f32x4 oAcc[4] = {};
    float mrun = -3.0e38f;
    float lrun = 0.0f;

    for (int kt = 0; kt < 8; ++kt) {
        __syncthreads();
        // ---- stage K tile (natural [kv][d], d-swizzled) ----
        {
            const float* kr = kbase + (size_t)(kt * 64 + skv) * kv_ts + sd;
            const f32x4 a0 = *(const f32x4*)(kr);
            const f32x4 a1 = *(const f32x4*)(kr + 4);
            const f32x4 a2 = *(const f32x4*)(kr + 8);
            const f32x4 a3 = *(const f32x4*)(kr + 12);
            bf16x8 h0, h1, l0, l1;
            #pragma unroll
            for (int j = 0; j < 4; ++j) {
                const short ha = bhi(a0[j]), hb = bhi(a1[j]);
                const short hc = bhi(a2[j]), hd = bhi(a3[j]);
                h0[j] = ha; h0[j + 4] = hb; h1[j] = hc; h1[j + 4] = hd;
                l0[j]     = bhi(bresid(a0[j], ha));
                l0[j + 4] = bhi(bresid(a1[j], hb));
                l1[j]     = bhi(bresid(a2[j], hc));
                l1[j + 4] = bhi(bresid(a3[j], hd));
            }
            const int base = skv * 64;
            *(bf16x8*)&Kth[base + (sd ^ ksw)]       = h0;
            *(bf16x8*)&Kth[base + ((sd + 8) ^ ksw)] = h1;
            *(bf16x8*)&Ktl[base + (sd ^ ksw)]       = l0;
            *(bf16x8*)&Ktl[base + ((sd + 8) ^ ksw)] = l1;
        }
        // ---- stage V^T tile ([d][kv], kv-swizzled), 4x4 transpose ----
        {
            const float* vr = vbase + (size_t)(kt * 64 + vkv) * kv_ts + vd;
            const f32x4 r0 = *(const f32x4*)(vr);
            const f32x4 r1 = *(const f32x4*)(vr + kv_ts);
            const f32x4 r2 = *(const f32x4*)(vr + 2 * (size_t)kv_ts);
            const f32x4 r3 = *(const f32x4*)(vr + 3 * (size_t)kv_ts);
            #pragma unroll
            for (int j = 0; j < 4; ++j) {
                const int dd = vd + j;
                short4v hv, lv;
                const short e0 = bhi(r0[j]), e1 = bhi(r1[j]);
                const short e2 = bhi(r2[j]), e3 = bhi(r3[j]);
                hv[0] = e0; hv[1] = e1; hv[2] = e2; hv[3] = e3;
                lv[0] = bhi(bresid(r0[j], e0));
                lv[1] = bhi(bresid(r1[j], e1));
                lv[2] = bhi(bresid(r2[j], e2));
                lv[3] = bhi(bresid(r3[j], e3));
                const int off = dd * 64 + (vkv ^ ((dd & 7) << 3));
                *(short4v*)&Vth[off] = hv;
                *(short4v*)&Vtl[off] = lv;
            }
        }
        __syncthreads();

        // ---- QK^T (swapped): S^T[kv][q], rows kv = st*16+g4*4+r, col q=r16 ----
        f32x4 s4[4] = {};
        #pragma unroll
        for (int st = 0; st < 4; ++st) {
            const int kvl = st * 16 + r16;
            const int ssw = (kvl & 7) << 3;
            #pragma unroll
            for (int ks = 0; ks < 2; ++ks) {
                const int off = kvl * 64 + ((ks * 32 + g4 * 8) ^ ssw);
                const bf16x8 kh = *(const bf16x8*)&Kth[off];
                const bf16x8 kl = *(const bf16x8*)&Ktl[off];
                s4[st] = __builtin_amdgcn_mfma_f32_16x16x32_bf16(kh, qh[ks], s4[st], 0, 0, 0);
                s4[st] = __builtin_amdgcn_mfma_f32_16x16x32_bf16(kl, qh[ks], s4[st], 0, 0, 0);
                s4[st] = __builtin_amdgcn_mfma_f32_16x16x32_bf16(kh, ql[ks], s4[st], 0, 0, 0);
            }
        }

        // ---- online softmax update (exp2 domain) ----
        float tmax = -3.0e38f;
        #pragma unroll
        for (int st = 0; st < 4; ++st)
            #pragma unroll
            for (int r = 0; r < 4; ++r) tmax = fmaxf(tmax, s4[st][r]);
        tmax = fmaxf(tmax, __shfl_xor(tmax, 16));
        tmax = fmaxf(tmax, __shfl_xor(tmax, 32));
        const float mnew = fmaxf(mrun, tmax);
        const float fscale = exp2f(mrun - mnew);
        float psum = 0.0f;
        #pragma unroll
        for (int st = 0; st < 4; ++st)
            #pragma unroll
            for (int r = 0; r < 4; ++r) {
                const float e = exp2f(s4[st][r] - mnew);
                s4[st][r] = e;
                psum += e;
            }
        psum += __shfl_xor(psum, 16);
        psum += __shfl_xor(psum, 32);
        lrun = lrun * fscale + psum;
        mrun = mnew;
        #pragma unroll
        for (int dt = 0; dt < 4; ++dt) oAcc[dt] *= fscale;

        // ---- write P tile (hi/lo), rows = this wave's q ----
        #pragma unroll
        for (int st = 0; st < 4; ++st) {
            short4v ph, pl;
            #pragma unroll
            for (int r = 0; r < 4; ++r) {
                const short hi = bhi(s4[st][r]);
                ph[r] = hi;
                pl[r] = bhi(bresid(s4[st][r], hi));
            }
            const int off = myq * 64 + ((st * 16 + g4 * 4) ^ qsw);
            *(short4v*)&Pth[off] = ph;
            *(short4v*)&Ptl[off] = pl;
        }

        // ---- PV: O^T[d][q] += Vt * P (3-term split) ----
        #pragma unroll
        for (int ks = 0; ks < 2; ++ks) {
            const int poff = myq * 64 + ((ks * 32 + g4 * 8) ^ qsw);
            const bf16x8 pf_h = *(const bf16x8*)&Pth[poff];
            const bf16x8 pf_l = *(const bf16x8*)&Ptl[poff];
            #pragma unroll
            for (int dt = 0; dt < 4; ++dt) {
                const int dd = dt * 16 + r16;
                const int voff = dd * 64 + ((ks * 32 + g4 * 8) ^ ((dd & 7) << 3));
                const bf16x8 vh = *(const bf16x8*)&Vth[voff];
                const bf16x8 vl = *(const bf16x8*)&Vtl[voff];
                oAcc[dt] = __builtin_amdgcn_mfma_f32_16x16x32_bf16(vh, pf_h, oAcc[dt], 0, 0, 0);
                oAcc[dt] = __builtin_amdgcn_mfma_f32_16x16x32_bf16(vl, pf_h, oAcc[dt], 0, 0, 0);
                oAcc[dt] = __builtin_amdgcn_mfma_f32_16x16x32_bf16(vh, pf_l, oAcc[dt], 0, 0, 0);
            }
        }
    }

    // ---- epilogue: normalize and store O[q][d] (float4 per dt) ----
    const float inv = 1.0f / lrun;
    float* orow = Op + (size_t)(b * LQc + q0 + myq) * Dc + h * HDc;
    #pragma unroll
    for (int dt = 0; dt < 4; ++dt) {
        float4 st;
        st.x = oAcc[dt][0] * inv;
        st.y = oAcc[dt][1] * inv;
        st.z = oAcc[dt][2] * inv;
        st.w = oAcc[dt][3] * inv;
        *(float4*)&orow[dt * 16 + g4 * 4] = st;
    }
}

} // anonymous namespace

// ----------------------------------------------------------------------------
// Launcher
// ----------------------------------------------------------------------------
extern "C" void kernel_launch(void* const* d_in, const int* in_sizes, int n_in,
                              void* d_out, int out_size, void* d_ws, size_t ws_size,
                              hipStream_t stream)
{
    const float* q_in   = (const float*)d_in[0];
    const float* kv_in  = (const float*)d_in[1];
    const float* n1g    = (const float*)d_in[2];
    const float* n1b    = (const float*)d_in[3];
    const float* qkv_w  = (const float*)d_in[4];
    const float* sa_w   = (const float*)d_in[5];
    const float* sa_b   = (const float*)d_in[6];
    const float* n2qg   = (const float*)d_in[7];
    const float* n2qb   = (const float*)d_in[8];
    const float* n2kg   = (const float*)d_in[9];
    const float* n2kb   = (const float*)d_in[10];
    const float* caq_w  = (const float*)d_in[11];
    const float* cakv_w = (const float*)d_in[12];
    const float* cap_w  = (const float*)d_in[13];
    const float* cap_b  = (const float*)d_in[14];
    const float* n3g    = (const float*)d_in[15];
    const float* n3b    = (const float*)d_in[16];
    const float* fc1_w  = (const float*)d_in[17];
    const float* fc1_b  = (const float*)d_in[18];
    const float* fc2_w  = (const float*)d_in[19];
    const float* fc2_b  = (const float*)d_in[20];
    float* out = (float*)d_out;

    const size_t MQ = (size_t)Bc * LQc * Dc;
    float* ws      = (float*)d_ws;
    float* bufA    = ws;
    float* bufB    = ws + MQ;
    float* bufC    = ws + 2 * MQ;
    float* bufBig  = ws + 3 * MQ;

    const int ROWS = Bc * LQc;
    const dim3 blk(256);
    const dim3 lnGrid(ROWS);
    const dim3 attnGrid(Bc * Hc * (LQc / 64));   // 1536

    // 1. x1 = LN1(q)
    ln_kernel<<<lnGrid, blk, 0, stream>>>(q_in, n1g, n1b, bufA);
    // 2. qkv = x1 @ qkv_w^T
    gemm_nt_mfma<<<dim3((3 * Dc) / 128, ROWS / 128), blk, 0, stream>>>(
        bufA, qkv_w, nullptr, nullptr, bufBig, ROWS, 3 * Dc, Dc, 0);
    // 3. sa_out = attend(q,k,v)    -> bufB
    attn_mfma<<<attnGrid, blk, 0, stream>>>(
        bufBig, bufBig + Dc, bufBig + 2 * Dc, bufB,
        3 * Dc, 3 * Dc, (long long)LQc * 3 * Dc, (long long)LKVc * 3 * Dc);
    // 4. q1 = sa_out @ sa_w^T + sa_b + q     -> out
    gemm_nt_mfma<<<dim3(Dc / 128, ROWS / 128), blk, 0, stream>>>(
        bufB, sa_w, sa_b, q_in, out, ROWS, Dc, Dc, 0);
    // 5. xq = LN2q(q1)
    ln_kernel<<<lnGrid, blk, 0, stream>>>(out, n2qg, n2qb, bufA);
    // 6. xkv = LN2kv(kv)
    ln_kernel<<<lnGrid, blk, 0, stream>>>(kv_in, n2kg, n2kb, bufC);
    // 7. qc = xq @ caq_w^T         -> bufB
    gemm_nt_mfma<<<dim3(Dc / 128, ROWS / 128), blk, 0, stream>>>(
        bufA, caq_w, nullptr, nullptr, bufB, ROWS, Dc, Dc, 0);
    // 8. kvc = xkv @ cakv_w^T      -> bufBig
    gemm_nt_mfma<<<dim3((2 * Dc) / 128, ROWS / 128), blk, 0, stream>>>(
        bufC, cakv_w, nullptr, nullptr, bufBig, ROWS, 2 * Dc, Dc, 0);
    // 9. ca_out = attend(qc, kc, vc) -> bufA
    attn_mfma<<<attnGrid, blk, 0, stream>>>(
        bufB, bufBig, bufBig + Dc, bufA,
        Dc, 2 * Dc, (long long)LQc * Dc, (long long)LKVc * 2 * Dc);
    // 10. q2 = ca_out @ cap_w^T + cap_b + q1  -> out
    gemm_nt_mfma<<<dim3(Dc / 128, ROWS / 128), blk, 0, stream>>>(
        bufA, cap_w, cap_b, out, out, ROWS, Dc, Dc, 0);
    // 11. x3 = LN3(q2)
    ln_kernel<<<lnGrid, blk, 0, stream>>>(out, n3g, n3b, bufA);
    // 12. hmid = gelu(x3 @ fc1^T + fc1_b)     -> bufBig
    gemm_nt_mfma<<<dim3(HIDc / 128, ROWS / 128), blk, 0, stream>>>(
        bufA, fc1_w, fc1_b, nullptr, bufBig, ROWS, HIDc, Dc, 1);
    // 13. out = hmid @ fc2^T + fc2_b + q2
    gemm_nt_mfma<<<dim3(Dc / 128, ROWS / 128), blk, 0, stream>>>(
        bufBig, fc2_w, fc2_b, out, out, ROWS, Dc, HIDc, 0);
}

// Round 4
// 1052.654 us; speedup vs baseline: 3.6016x; 1.1251x over previous
//
#include <hip/hip_runtime.h>

namespace {

constexpr int Bc   = 16;
constexpr int LQc  = 512;
constexpr int LKVc = 512;
constexpr int Dc   = 768;
constexpr int Hc   = 12;
constexpr int HDc  = 64;
constexpr int HIDc = 3072;

using bf16x8  = __attribute__((ext_vector_type(8))) short;
using short4v = __attribute__((ext_vector_type(4))) short;
using f32x4   = __attribute__((ext_vector_type(4))) float;

__device__ inline short f2bf(float x) {              // round-to-nearest-even
    union { float f; unsigned u; } v; v.f = x;
    const unsigned r = v.u + 0x7fffu + ((v.u >> 16) & 1u);
    return (short)(r >> 16);
}
__device__ inline float bf2f(short h) {
    union { unsigned u; float f; } v;
    v.u = ((unsigned)(unsigned short)h) << 16;
    return v.f;
}
__device__ inline short bhi(float x) {               // truncating bf16 (hot loop)
    union { float f; unsigned u; } v; v.f = x;
    return (short)(v.u >> 16);
}
__device__ inline float bresid(float x, short hi) { return x - bf2f(hi); }
__device__ inline void splitRT(float x, short& h, short& l) {
    h = f2bf(x);
    l = f2bf(x - bf2f(h));
}
__device__ inline void gload16(const void* g, void* lds) {
    __builtin_amdgcn_global_load_lds(
        (const __attribute__((address_space(1))) unsigned int*)g,
        (__attribute__((address_space(3))) unsigned int*)lds, 16, 0, 0);
}

// ----------------------------------------------------------------------------
// Weight pre-split: fp32 -> bf16 hi/lo, 7 tensors in one launch.
// ----------------------------------------------------------------------------
struct SplitArgs {
    const float* src[7];
    short* dh[7];
    short* dl[7];
    int cum4[8];     // cumulative float4 counts
};

__global__ __launch_bounds__(256) void split_w(SplitArgs a) {
    const int total = a.cum4[7];
    for (int i = blockIdx.x * 256 + threadIdx.x; i < total; i += gridDim.x * 256) {
        int s = 0;
        while (i >= a.cum4[s + 1]) ++s;
        const int off = i - a.cum4[s];
        const f32x4 v = *((const f32x4*)a.src[s] + off);
        short4v h, l;
        #pragma unroll
        for (int j = 0; j < 4; ++j) { short hh, ll; splitRT(v[j], hh, ll); h[j] = hh; l[j] = ll; }
        *((short4v*)a.dh[s] + off) = h;
        *((short4v*)a.dl[s] + off) = l;
    }
}

// ----------------------------------------------------------------------------
// LayerNorm: one block per row; emits bf16 hi/lo pair.
// ----------------------------------------------------------------------------
__global__ __launch_bounds__(256) void ln_kernel(
    const float* __restrict__ X, const float* __restrict__ g,
    const float* __restrict__ bta, short* __restrict__ Yh, short* __restrict__ Yl)
{
    const int row = blockIdx.x;
    const float* x = X + (size_t)row * Dc;
    const int t = threadIdx.x;
    const float v0 = x[t], v1 = x[t + 256], v2 = x[t + 512];
    float s  = v0 + v1 + v2;
    float ss = v0 * v0 + v1 * v1 + v2 * v2;
    #pragma unroll
    for (int off = 32; off > 0; off >>= 1) {
        s  += __shfl_down(s, off);
        ss += __shfl_down(ss, off);
    }
    __shared__ float red[8];
    __shared__ float mv[2];
    const int wid = t >> 6;
    if ((t & 63) == 0) { red[wid] = s; red[wid + 4] = ss; }
    __syncthreads();
    if (t == 0) {
        const float S  = red[0] + red[1] + red[2] + red[3];
        const float SS = red[4] + red[5] + red[6] + red[7];
        const float mean = S * (1.0f / Dc);
        const float var  = SS * (1.0f / Dc) - mean * mean;
        mv[0] = mean;
        mv[1] = rsqrtf(var + 1e-5f);
    }
    __syncthreads();
    const float mean = mv[0], inv = mv[1];
    short h0, l0, h1, l1, h2, l2;
    splitRT((v0 - mean) * inv * g[t]       + bta[t],       h0, l0);
    splitRT((v1 - mean) * inv * g[t + 256] + bta[t + 256], h1, l1);
    splitRT((v2 - mean) * inv * g[t + 512] + bta[t + 512], h2, l2);
    const size_t rb = (size_t)row * Dc;
    Yh[rb + t] = h0;        Yl[rb + t] = l0;
    Yh[rb + t + 256] = h1;  Yl[rb + t + 256] = l1;
    Yh[rb + t + 512] = h2;  Yl[rb + t + 512] = l2;
}

// ----------------------------------------------------------------------------
// MFMA GEMM (NT) on pre-split bf16 hi/lo inputs. Tile BM x 128, BK=32,
// 256 threads (4 waves). global_load_lds staging (linear LDS, m97 structure).
// 3-term hi/lo MFMA (hh + lh + hl), fp32 accumulate.
// BM=128: waves 2x2, 64x64 each. BM=64: waves 1x4, 64x32 each.
// Output: fp32 (+bias+resid) or bf16 pair (+bias+gelu).
// ----------------------------------------------------------------------------
template<int BM>
__global__ __launch_bounds__(256) void gemm_bf3(
    const short* __restrict__ Ahp, const short* __restrict__ Alp,
    const short* __restrict__ Whp, const short* __restrict__ Wlp,
    const float* __restrict__ bias, const float* __restrict__ resid,
    float* __restrict__ Cf, short* __restrict__ Ch, short* __restrict__ Cl,
    int M, int N, int K, int act)
{
    constexpr int CW = (BM == 128) ? 64 : 32;   // wave col width
    constexpr int FB = CW / 16;                 // B frags per wave
    constexpr int NA = BM / 64;                 // A wave-chunks per wave

    __shared__ __attribute__((aligned(16))) short sAh[BM * 32];
    __shared__ __attribute__((aligned(16))) short sAl[BM * 32];
    __shared__ __attribute__((aligned(16))) short sWh[128 * 32];
    __shared__ __attribute__((aligned(16))) short sWl[128 * 32];

    const int t    = threadIdx.x;
    const int lane = t & 63;
    const int wv   = t >> 6;
    const int wr   = (BM == 128) ? (wv >> 1) : 0;
    const int wc   = (BM == 128) ? (wv & 1) : wv;
    const int r16  = lane & 15;
    const int g4   = lane >> 4;
    const int m0   = blockIdx.y * BM;
    const int n0   = blockIdx.x * 128;

    // staging pointers (wave-chunk = 1KB = 64 lanes x 16B; row stride 32 bf16)
    const short* pAh[NA]; const short* pAl[NA];
    short* dAh[NA]; short* dAl[NA];
    #pragma unroll
    for (int j = 0; j < NA; ++j) {
        const int i = (wv * NA + j) * 64 + lane;
        const int r = i >> 2, c8 = (i & 3) * 8;
        pAh[j] = Ahp + (size_t)(m0 + r) * K + c8;
        pAl[j] = Alp + (size_t)(m0 + r) * K + c8;
        dAh[j] = &sAh[(wv * NA + j) * 512];
        dAl[j] = &sAl[(wv * NA + j) * 512];
    }
    const short* pWh[2]; const short* pWl[2];
    short* dWh[2]; short* dWl[2];
    #pragma unroll
    for (int j = 0; j < 2; ++j) {
        const int i = (wv * 2 + j) * 64 + lane;
        const int r = i >> 2, c8 = (i & 3) * 8;
        pWh[j] = Whp + (size_t)(n0 + r) * K + c8;
        pWl[j] = Wlp + (size_t)(n0 + r) * K + c8;
        dWh[j] = &sWh[(wv * 2 + j) * 512];
        dWl[j] = &sWl[(wv * 2 + j) * 512];
    }

    f32x4 acc[4][FB] = {};

    for (int k0 = 0; k0 < K; k0 += 32) {
        #pragma unroll
        for (int j = 0; j < NA; ++j) {
            gload16(pAh[j] + k0, dAh[j]);
            gload16(pAl[j] + k0, dAl[j]);
        }
        #pragma unroll
        for (int j = 0; j < 2; ++j) {
            gload16(pWh[j] + k0, dWh[j]);
            gload16(pWl[j] + k0, dWl[j]);
        }
        __syncthreads();   // drains vmcnt: LDS tiles ready

        bf16x8 fah[4], fal[4], fbh[FB], fbl[FB];
        #pragma unroll
        for (int f = 0; f < 4; ++f) {
            const int ar = (wr * 64 + f * 16 + r16) * 32 + g4 * 8;
            fah[f] = *(const bf16x8*)&sAh[ar];
            fal[f] = *(const bf16x8*)&sAl[ar];
        }
        #pragma unroll
        for (int f = 0; f < FB; ++f) {
            const int br = (wc * CW + f * 16 + r16) * 32 + g4 * 8;
            fbh[f] = *(const bf16x8*)&sWh[br];
            fbl[f] = *(const bf16x8*)&sWl[br];
        }

        #pragma unroll
        for (int i = 0; i < 4; ++i)
            #pragma unroll
            for (int j = 0; j < FB; ++j) {
                acc[i][j] = __builtin_amdgcn_mfma_f32_16x16x32_bf16(
                    fah[i], fbh[j], acc[i][j], 0, 0, 0);
                acc[i][j] = __builtin_amdgcn_mfma_f32_16x16x32_bf16(
                    fal[i], fbh[j], acc[i][j], 0, 0, 0);
                acc[i][j] = __builtin_amdgcn_mfma_f32_16x16x32_bf16(
                    fah[i], fbl[j], acc[i][j], 0, 0, 0);
            }
        __syncthreads();   // frag reads done before next overwrite
    }

    #pragma unroll
    for (int i = 0; i < 4; ++i) {
        const int grow = m0 + wr * 64 + i * 16 + g4 * 4;
        #pragma unroll
        for (int j = 0; j < FB; ++j) {
            const int gcol = n0 + wc * CW + j * 16 + r16;
            const float bv = bias ? bias[gcol] : 0.0f;
            #pragma unroll
            for (int r = 0; r < 4; ++r) {
                float v = acc[i][j][r] + bv;
                if (act) v = 0.5f * v * (1.0f + erff(v * 0.70710678118654752f));
                const size_t off = (size_t)(grow + r) * N + gcol;
                if (Ch) {
                    short h_, l_; splitRT(v, h_, l_);
                    Ch[off] = h_; Cl[off] = l_;
                } else {
                    if (resid) v += resid[off];
                    Cf[off] = v;
                }
            }
        }
    }
}

// ----------------------------------------------------------------------------
// MFMA flash attention on pre-split bf16 hi/lo Q/K/V; emits bf16 hi/lo O.
// Block = 256 thr (4 waves), 64 q rows. Swapped QK^T, online softmax.
// Scale folded into softmax (post-MFMA, exact). XOR-swizzled LDS.
// ----------------------------------------------------------------------------
__global__ __launch_bounds__(256) void attn_mfma(
    const short* __restrict__ Qh_, const short* __restrict__ Ql_,
    const short* __restrict__ Kh_, const short* __restrict__ Kl_,
    const short* __restrict__ Vh_, const short* __restrict__ Vl_,
    short* __restrict__ Oh_, short* __restrict__ Ol_,
    int q_ts, int kv_ts, long long q_bs, long long kv_bs)
{
    __shared__ __attribute__((aligned(16))) short Kth[64 * 64];
    __shared__ __attribute__((aligned(16))) short Ktl[64 * 64];
    __shared__ __attribute__((aligned(16))) short Vth[64 * 64];
    __shared__ __attribute__((aligned(16))) short Vtl[64 * 64];
    __shared__ __attribute__((aligned(16))) short Pth[64 * 64];
    __shared__ __attribute__((aligned(16))) short Ptl[64 * 64];

    const int t    = threadIdx.x;
    const int lane = t & 63;
    const int w    = t >> 6;
    const int r16  = lane & 15;
    const int g4   = lane >> 4;

    int bid = blockIdx.x;
    const int qt = bid & 7;  bid >>= 3;
    const int h  = bid % Hc;
    const int b  = bid / Hc;
    const int q0 = qt * 64;

    const int myq = w * 16 + r16;
    const int qsw = (myq & 7) << 3;

    // Q fragments straight from pre-split buffers
    bf16x8 qh[2], ql[2];
    {
        const short* qrh = Qh_ + (size_t)b * q_bs + (size_t)(q0 + myq) * q_ts + h * HDc;
        const short* qrl = Ql_ + (size_t)b * q_bs + (size_t)(q0 + myq) * q_ts + h * HDc;
        #pragma unroll
        for (int ks = 0; ks < 2; ++ks) {
            qh[ks] = *(const bf16x8*)(qrh + ks * 32 + g4 * 8);
            ql[ks] = *(const bf16x8*)(qrl + ks * 32 + g4 * 8);
        }
    }

    const short* kbh = Kh_ + (size_t)b * kv_bs + h * HDc;
    const short* kbl = Kl_ + (size_t)b * kv_bs + h * HDc;
    const short* vbh = Vh_ + (size_t)b * kv_bs + h * HDc;
    const short* vbl = Vl_ + (size_t)b * kv_bs + h * HDc;

    const int skv = t >> 2,       sd = (t & 3) * 16;
    const int vkv = (t >> 4) * 4, vd = (t & 15) * 4;
    const int ksw = (skv & 7) << 3;
    const float qsc = 0.125f * 1.44269504088896340736f;   // hd^-0.5 * log2(e)

    f32x4 oAcc[4] = {};
    float mrun = -3.0e38f;
    float lrun = 0.0f;

    for (int kt = 0; kt < 8; ++kt) {
        __syncthreads();
        // ---- stage K tile (copy 16B chunks, d-swizzled) ----
        {
            const short* kr_h = kbh + (size_t)(kt * 64 + skv) * kv_ts + sd;
            const short* kr_l = kbl + (size_t)(kt * 64 + skv) * kv_ts + sd;
            const int base = skv * 64;
            *(bf16x8*)&Kth[base + (sd ^ ksw)]       = *(const bf16x8*)(kr_h);
            *(bf16x8*)&Kth[base + ((sd + 8) ^ ksw)] = *(const bf16x8*)(kr_h + 8);
            *(bf16x8*)&Ktl[base + (sd ^ ksw)]       = *(const bf16x8*)(kr_l);
            *(bf16x8*)&Ktl[base + ((sd + 8) ^ ksw)] = *(const bf16x8*)(kr_l + 8);
        }
        // ---- stage V^T tile (4x4 bf16 transpose, kv-swizzled) ----
        {
            const short* vr_h = vbh + (size_t)(kt * 64 + vkv) * kv_ts + vd;
            const short* vr_l = vbl + (size_t)(kt * 64 + vkv) * kv_ts + vd;
            short4v h0 = *(const short4v*)(vr_h);
            short4v h1 = *(const short4v*)(vr_h + kv_ts);
            short4v h2 = *(const short4v*)(vr_h + 2 * (size_t)kv_ts);
            short4v h3 = *(const short4v*)(vr_h + 3 * (size_t)kv_ts);
            short4v l0 = *(const short4v*)(vr_l);
            short4v l1 = *(const short4v*)(vr_l + kv_ts);
            short4v l2 = *(const short4v*)(vr_l + 2 * (size_t)kv_ts);
            short4v l3 = *(const short4v*)(vr_l + 3 * (size_t)kv_ts);
            #pragma unroll
            for (int j = 0; j < 4; ++j) {
                const int dd = vd + j;
                short4v hv, lv;
                hv[0] = h0[j]; hv[1] = h1[j]; hv[2] = h2[j]; hv[3] = h3[j];
                lv[0] = l0[j]; lv[1] = l1[j]; lv[2] = l2[j]; lv[3] = l3[j];
                const int off = dd * 64 + (vkv ^ ((dd & 7) << 3));
                *(short4v*)&Vth[off] = hv;
                *(short4v*)&Vtl[off] = lv;
            }
        }
        __syncthreads();

        // ---- swapped QK^T: S^T[kv][q] ----
        f32x4 s4[4] = {};
        #pragma unroll
        for (int st = 0; st < 4; ++st) {
            const int kvl = st * 16 + r16;
            const int ssw = (kvl & 7) << 3;
            #pragma unroll
            for (int ks = 0; ks < 2; ++ks) {
                const int off = kvl * 64 + ((ks * 32 + g4 * 8) ^ ssw);
                const bf16x8 kh = *(const bf16x8*)&Kth[off];
                const bf16x8 kl = *(const bf16x8*)&Ktl[off];
                s4[st] = __builtin_amdgcn_mfma_f32_16x16x32_bf16(kh, qh[ks], s4[st], 0, 0, 0);
                s4[st] = __builtin_amdgcn_mfma_f32_16x16x32_bf16(kl, qh[ks], s4[st], 0, 0, 0);
                s4[st] = __builtin_amdgcn_mfma_f32_16x16x32_bf16(kh, ql[ks], s4[st], 0, 0, 0);
            }
        }
        // fold scale (exp2 domain)
        #pragma unroll
        for (int st = 0; st < 4; ++st)
            #pragma unroll
            for (int r = 0; r < 4; ++r) s4[st][r] *= qsc;

        // ---- online softmax ----
        float tmax = -3.0e38f;
        #pragma unroll
        for (int st = 0; st < 4; ++st)
            #pragma unroll
            for (int r = 0; r < 4; ++r) tmax = fmaxf(tmax, s4[st][r]);
        tmax = fmaxf(tmax, __shfl_xor(tmax, 16));
        tmax = fmaxf(tmax, __shfl_xor(tmax, 32));
        const float mnew = fmaxf(mrun, tmax);
        const float fscale = exp2f(mrun - mnew);
        float psum = 0.0f;
        #pragma unroll
        for (int st = 0; st < 4; ++st)
            #pragma unroll
            for (int r = 0; r < 4; ++r) {
                const float e = exp2f(s4[st][r] - mnew);
                s4[st][r] = e;
                psum += e;
            }
        psum += __shfl_xor(psum, 16);
        psum += __shfl_xor(psum, 32);
        lrun = lrun * fscale + psum;
        mrun = mnew;
        #pragma unroll
        for (int dt = 0; dt < 4; ++dt) oAcc[dt] *= fscale;

        // ---- write P tile (hi/lo, truncating split) ----
        #pragma unroll
        for (int st = 0; st < 4; ++st) {
            short4v ph, pl;
            #pragma unroll
            for (int r = 0; r < 4; ++r) {
                const short hi = bhi(s4[st][r]);
                ph[r] = hi;
                pl[r] = bhi(bresid(s4[st][r], hi));
            }
            const int off = myq * 64 + ((st * 16 + g4 * 4) ^ qsw);
            *(short4v*)&Pth[off] = ph;
            *(short4v*)&Ptl[off] = pl;
        }

        // ---- PV: O^T[d][q] += Vt * P ----
        #pragma unroll
        for (int ks = 0; ks < 2; ++ks) {
            const int poff = myq * 64 + ((ks * 32 + g4 * 8) ^ qsw);
            const bf16x8 pf_h = *(const bf16x8*)&Pth[poff];
            const bf16x8 pf_l = *(const bf16x8*)&Ptl[poff];
            #pragma unroll
            for (int dt = 0; dt < 4; ++dt) {
                const int dd = dt * 16 + r16;
                const int voff = dd * 64 + ((ks * 32 + g4 * 8) ^ ((dd & 7) << 3));
                const bf16x8 vh = *(const bf16x8*)&Vth[voff];
                const bf16x8 vl = *(const bf16x8*)&Vtl[voff];
                oAcc[dt] = __builtin_amdgcn_mfma_f32_16x16x32_bf16(vh, pf_h, oAcc[dt], 0, 0, 0);
                oAcc[dt] = __builtin_amdgcn_mfma_f32_16x16x32_bf16(vl, pf_h, oAcc[dt], 0, 0, 0);
                oAcc[dt] = __builtin_amdgcn_mfma_f32_16x16x32_bf16(vh, pf_l, oAcc[dt], 0, 0, 0);
            }
        }
    }

    // ---- epilogue: normalize, split, store bf16 pair ----
    const float inv = 1.0f / lrun;
    short* orh = Oh_ + (size_t)(b * LQc + q0 + myq) * Dc + h * HDc;
    short* orl = Ol_ + (size_t)(b * LQc + q0 + myq) * Dc + h * HDc;
    #pragma unroll
    for (int dt = 0; dt < 4; ++dt) {
        short4v hv, lv;
        #pragma unroll
        for (int r = 0; r < 4; ++r) {
            short h_, l_;
            splitRT(oAcc[dt][r] * inv, h_, l_);
            hv[r] = h_; lv[r] = l_;
        }
        *(short4v*)&orh[dt * 16 + g4 * 4] = hv;
        *(short4v*)&orl[dt * 16 + g4 * 4] = lv;
    }
}

} // anonymous namespace

// ----------------------------------------------------------------------------
// Launcher
// ----------------------------------------------------------------------------
extern "C" void kernel_launch(void* const* d_in, const int* in_sizes, int n_in,
                              void* d_out, int out_size, void* d_ws, size_t ws_size,
                              hipStream_t stream)
{
    const float* q_in   = (const float*)d_in[0];
    const float* kv_in  = (const float*)d_in[1];
    const float* n1g    = (const float*)d_in[2];
    const float* n1b    = (const float*)d_in[3];
    const float* qkv_w  = (const float*)d_in[4];
    const float* sa_w   = (const float*)d_in[5];
    const float* sa_b   = (const float*)d_in[6];
    const float* n2qg   = (const float*)d_in[7];
    const float* n2qb   = (const float*)d_in[8];
    const float* n2kg   = (const float*)d_in[9];
    const float* n2kb   = (const float*)d_in[10];
    const float* caq_w  = (const float*)d_in[11];
    const float* cakv_w = (const float*)d_in[12];
    const float* cap_w  = (const float*)d_in[13];
    const float* cap_b  = (const float*)d_in[14];
    const float* n3g    = (const float*)d_in[15];
    const float* n3b    = (const float*)d_in[16];
    const float* fc1_w  = (const float*)d_in[17];
    const float* fc1_b  = (const float*)d_in[18];
    const float* fc2_w  = (const float*)d_in[19];
    const float* fc2_b  = (const float*)d_in[20];
    float* out = (float*)d_out;

    const size_t MQ = (size_t)Bc * LQc * Dc;         // 6,291,456 elems

    // weight sizes (elements)
    const int wqkv = 3 * Dc * Dc, wsa = Dc * Dc, wcaq = Dc * Dc,
              wcakv = 2 * Dc * Dc, wcap = Dc * Dc,
              wfc1 = HIDc * Dc, wfc2 = Dc * HIDc;

    short* wsS = (short*)d_ws;
    size_t off = 0;
    auto alloc = [&](size_t n) { short* p = wsS + off; off += n; return p; };

    short* WqkvH  = alloc(wqkv);  short* WqkvL  = alloc(wqkv);
    short* WsaH   = alloc(wsa);   short* WsaL   = alloc(wsa);
    short* WcaqH  = alloc(wcaq);  short* WcaqL  = alloc(wcaq);
    short* WcakvH = alloc(wcakv); short* WcakvL = alloc(wcakv);
    short* WcapH  = alloc(wcap);  short* WcapL  = alloc(wcap);
    short* Wfc1H  = alloc(wfc1);  short* Wfc1L  = alloc(wfc1);
    short* Wfc2H  = alloc(wfc2);  short* Wfc2L  = alloc(wfc2);
    short* P1H    = alloc(MQ);    short* P1L    = alloc(MQ);
    short* bigH   = alloc(4 * MQ);
    short* bigL   = alloc(4 * MQ);
    // big region reuse: qkv pair [0,3MQ) -> xkv pair [2MQ,3MQ) + kvc [0,2MQ)
    //                   + qc [3MQ,4MQ) -> hidden [0,4MQ)
    short* xkvH = bigH + 2 * MQ;  short* xkvL = bigL + 2 * MQ;
    short* qcH  = bigH + 3 * MQ;  short* qcL  = bigL + 3 * MQ;

    const int ROWS = Bc * LQc;            // 8192
    const dim3 blk(256);
    const dim3 lnGrid(ROWS);
    const dim3 attnGrid(Bc * Hc * (LQc / 64));   // 1536

    // 0. split all weights once
    {
        SplitArgs a;
        const float* srcs[7] = {qkv_w, sa_w, caq_w, cakv_w, cap_w, fc1_w, fc2_w};
        short* dhs[7] = {WqkvH, WsaH, WcaqH, WcakvH, WcapH, Wfc1H, Wfc2H};
        short* dls[7] = {WqkvL, WsaL, WcaqL, WcakvL, WcapL, Wfc1L, Wfc2L};
        const int ns[7] = {wqkv, wsa, wcaq, wcakv, wcap, wfc1, wfc2};
        int c = 0;
        for (int i = 0; i < 7; ++i) {
            a.src[i] = srcs[i]; a.dh[i] = dhs[i]; a.dl[i] = dls[i];
            a.cum4[i] = c; c += ns[i] / 4;
        }
        a.cum4[7] = c;
        split_w<<<dim3(1024), blk, 0, stream>>>(a);
    }

    // 1. x1 = LN1(q) -> P1
    ln_kernel<<<lnGrid, blk, 0, stream>>>(q_in, n1g, n1b, P1H, P1L);
    // 2. qkv = x1 @ qkv_w^T -> big pair [0,3MQ)
    gemm_bf3<128><<<dim3((3 * Dc) / 128, ROWS / 128), blk, 0, stream>>>(
        P1H, P1L, WqkvH, WqkvL, nullptr, nullptr,
        nullptr, bigH, bigL, ROWS, 3 * Dc, Dc, 0);
    // 3. sa_out = attend(q,k,v) -> P1
    attn_mfma<<<attnGrid, blk, 0, stream>>>(
        bigH, bigL, bigH + Dc, bigL + Dc, bigH + 2 * Dc, bigL + 2 * Dc,
        P1H, P1L, 3 * Dc, 3 * Dc, (long long)LQc * 3 * Dc, (long long)LKVc * 3 * Dc);
    // 4. q1 = sa_out @ sa_w^T + sa_b + q -> out (fp32)
    gemm_bf3<64><<<dim3(Dc / 128, ROWS / 64), blk, 0, stream>>>(
        P1H, P1L, WsaH, WsaL, sa_b, q_in,
        out, nullptr, nullptr, ROWS, Dc, Dc, 0);
    // 5. xq = LN2q(q1) -> P1
    ln_kernel<<<lnGrid, blk, 0, stream>>>(out, n2qg, n2qb, P1H, P1L);
    // 6. xkv = LN2kv(kv) -> big[2MQ,3MQ)
    ln_kernel<<<lnGrid, blk, 0, stream>>>(kv_in, n2kg, n2kb, xkvH, xkvL);
    // 7. qc = xq @ caq_w^T -> big[3MQ,4MQ)
    gemm_bf3<64><<<dim3(Dc / 128, ROWS / 64), blk, 0, stream>>>(
        P1H, P1L, WcaqH, WcaqL, nullptr, nullptr,
        nullptr, qcH, qcL, ROWS, Dc, Dc, 0);
    // 8. kvc = xkv @ cakv_w^T -> big[0,2MQ)
    gemm_bf3<128><<<dim3((2 * Dc) / 128, ROWS / 128), blk, 0, stream>>>(
        xkvH, xkvL, WcakvH, WcakvL, nullptr, nullptr,
        nullptr, bigH, bigL, ROWS, 2 * Dc, Dc, 0);
    // 9. ca_out = attend(qc, kc, vc) -> P1
    attn_mfma<<<attnGrid, blk, 0, stream>>>(
        qcH, qcL, bigH, bigL, bigH + Dc, bigL + Dc,
        P1H, P1L, Dc, 2 * Dc, (long long)LQc * Dc, (long long)LKVc * 2 * Dc);
    // 10. q2 = ca_out @ cap_w^T + cap_b + q1 -> out
    gemm_bf3<64><<<dim3(Dc / 128, ROWS / 64), blk, 0, stream>>>(
        P1H, P1L, WcapH, WcapL, cap_b, out,
        out, nullptr, nullptr, ROWS, Dc, Dc, 0);
    // 11. x3 = LN3(q2) -> P1
    ln_kernel<<<lnGrid, blk, 0, stream>>>(out, n3g, n3b, P1H, P1L);
    // 12. hidden = gelu(x3 @ fc1^T + fc1_b) -> big pair [0,4MQ)
    gemm_bf3<128><<<dim3(HIDc / 128, ROWS / 128), blk, 0, stream>>>(
        P1H, P1L, Wfc1H, Wfc1L, fc1_b, nullptr,
        nullptr, bigH, bigL, ROWS, HIDc, Dc, 1);
    // 13. out = hidden @ fc2^T + fc2_b + q2 -> out
    gemm_bf3<64><<<dim3(Dc / 128, ROWS / 64), blk, 0, stream>>>(
        bigH, bigL, Wfc2H, Wfc2L, fc2_b, out,
        out, nullptr, nullptr, ROWS, Dc, HIDc, 0);
}

// Round 5
// 929.662 us; speedup vs baseline: 4.0781x; 1.1323x over previous
//
#include <hip/hip_runtime.h>

namespace {

constexpr int Bc   = 16;
constexpr int LQc  = 512;
constexpr int LKVc = 512;
constexpr int Dc   = 768;
constexpr int Hc   = 12;
constexpr int HDc  = 64;
constexpr int HIDc = 3072;

using bf16x8  = __attribute__((ext_vector_type(8))) short;
using short4v = __attribute__((ext_vector_type(4))) short;
using f32x4   = __attribute__((ext_vector_type(4))) float;

__device__ inline short f2bf(float x) {              // round-to-nearest-even
    union { float f; unsigned u; } v; v.f = x;
    const unsigned r = v.u + 0x7fffu + ((v.u >> 16) & 1u);
    return (short)(r >> 16);
}
__device__ inline float bf2f(short h) {
    union { unsigned u; float f; } v;
    v.u = ((unsigned)(unsigned short)h) << 16;
    return v.f;
}
__device__ inline short bhi(float x) {               // truncating bf16 (hot loop)
    union { float f; unsigned u; } v; v.f = x;
    return (short)(v.u >> 16);
}
__device__ inline float bresid(float x, short hi) { return x - bf2f(hi); }
__device__ inline void splitRT(float x, short& h, short& l) {
    h = f2bf(x);
    l = f2bf(x - bf2f(h));
}
__device__ inline void gload16(const void* g, void* lds) {
    __builtin_amdgcn_global_load_lds(
        (const __attribute__((address_space(1))) unsigned int*)g,
        (__attribute__((address_space(3))) unsigned int*)lds, 16, 0, 0);
}

// ----------------------------------------------------------------------------
// Weight pre-split: fp32 -> bf16 hi/lo, 7 tensors in one launch.
// ----------------------------------------------------------------------------
struct SplitArgs {
    const float* src[7];
    short* dh[7];
    short* dl[7];
    int cum4[8];     // cumulative float4 counts
};

__global__ __launch_bounds__(256) void split_w(SplitArgs a) {
    const int total = a.cum4[7];
    for (int i = blockIdx.x * 256 + threadIdx.x; i < total; i += gridDim.x * 256) {
        int s = 0;
        while (i >= a.cum4[s + 1]) ++s;
        const int off = i - a.cum4[s];
        const f32x4 v = *((const f32x4*)a.src[s] + off);
        short4v h, l;
        #pragma unroll
        for (int j = 0; j < 4; ++j) { short hh, ll; splitRT(v[j], hh, ll); h[j] = hh; l[j] = ll; }
        *((short4v*)a.dh[s] + off) = h;
        *((short4v*)a.dl[s] + off) = l;
    }
}

// ----------------------------------------------------------------------------
// LayerNorm: one block per row; emits bf16 hi/lo pair.
// ----------------------------------------------------------------------------
__global__ __launch_bounds__(256) void ln_kernel(
    const float* __restrict__ X, const float* __restrict__ g,
    const float* __restrict__ bta, short* __restrict__ Yh, short* __restrict__ Yl)
{
    const int row = blockIdx.x;
    const float* x = X + (size_t)row * Dc;
    const int t = threadIdx.x;
    const float v0 = x[t], v1 = x[t + 256], v2 = x[t + 512];
    float s  = v0 + v1 + v2;
    float ss = v0 * v0 + v1 * v1 + v2 * v2;
    #pragma unroll
    for (int off = 32; off > 0; off >>= 1) {
        s  += __shfl_down(s, off);
        ss += __shfl_down(ss, off);
    }
    __shared__ float red[8];
    __shared__ float mv[2];
    const int wid = t >> 6;
    if ((t & 63) == 0) { red[wid] = s; red[wid + 4] = ss; }
    __syncthreads();
    if (t == 0) {
        const float S  = red[0] + red[1] + red[2] + red[3];
        const float SS = red[4] + red[5] + red[6] + red[7];
        const float mean = S * (1.0f / Dc);
        const float var  = SS * (1.0f / Dc) - mean * mean;
        mv[0] = mean;
        mv[1] = rsqrtf(var + 1e-5f);
    }
    __syncthreads();
    const float mean = mv[0], inv = mv[1];
    short h0, l0, h1, l1, h2, l2;
    splitRT((v0 - mean) * inv * g[t]       + bta[t],       h0, l0);
    splitRT((v1 - mean) * inv * g[t + 256] + bta[t + 256], h1, l1);
    splitRT((v2 - mean) * inv * g[t + 512] + bta[t + 512], h2, l2);
    const size_t rb = (size_t)row * Dc;
    Yh[rb + t] = h0;        Yl[rb + t] = l0;
    Yh[rb + t + 256] = h1;  Yl[rb + t + 256] = l1;
    Yh[rb + t + 512] = h2;  Yl[rb + t + 512] = l2;
}

// ----------------------------------------------------------------------------
// Unified MFMA GEMM (NT) on pre-split bf16 hi/lo. Tile 64x128, BK=64,
// 256 threads (4 waves, each 64x32). M fixed = 8192 (grid.y = 128).
// global_load_lds with pre-swizzled global source (LDS linear, reads XOR'd):
// LDS slot (row, c8) holds global col (c8 ^ ((row&7)*8)) -- kills the 16-way
// conflict of 128B-stride rows. XCD-chunked N-major block remap for L2 reuse.
// 3-term hi/lo MFMA (hh + lh + hl), fp32 accumulate.
// ----------------------------------------------------------------------------
__global__ __launch_bounds__(256, 3) void gemm_bf3(
    const short* __restrict__ Ahp, const short* __restrict__ Alp,
    const short* __restrict__ Whp, const short* __restrict__ Wlp,
    const float* __restrict__ bias, const float* __restrict__ resid,
    float* __restrict__ Cf, short* __restrict__ Ch, short* __restrict__ Cl,
    int N, int K, int act, int gx)
{
    __shared__ __attribute__((aligned(16))) short sAh[64 * 64];
    __shared__ __attribute__((aligned(16))) short sAl[64 * 64];
    __shared__ __attribute__((aligned(16))) short sWh[128 * 64];
    __shared__ __attribute__((aligned(16))) short sWl[128 * 64];

    const int t    = threadIdx.x;
    const int lane = t & 63;
    const int wv   = t >> 6;
    const int r16  = lane & 15;
    const int g4   = lane >> 4;

    // XCD-chunked, N-major remap (bijective: nwg = gx*128, %8==0)
    const int flat = blockIdx.x + gx * blockIdx.y;
    const int l    = (flat & 7) * (gx << 4) + (flat >> 3);
    const int by   = l & 127;          // M-block (fast within chunk)
    const int bx   = l >> 7;           // N-block
    const int m0   = by << 6;
    const int n0   = bx << 7;

    // ---- staging setup: 48 chunks of 1KB (8 rows x 64 shorts); 12 per wave ----
    const short* gsrc[12];
    short* ldst[12];
    {
        const int lrow = lane >> 3;
        const int col8 = (lane & 7) << 3;
        #pragma unroll
        for (int j = 0; j < 12; ++j) {
            const int c = wv * 12 + j;
            const short* src; short* buf; int row0, tile0;
            if (c < 8)       { src = Ahp; buf = sAh; row0 = c * 8;        tile0 = m0; }
            else if (c < 16) { src = Alp; buf = sAl; row0 = (c - 8) * 8;  tile0 = m0; }
            else if (c < 32) { src = Whp; buf = sWh; row0 = (c - 16) * 8; tile0 = n0; }
            else             { src = Wlp; buf = sWl; row0 = (c - 32) * 8; tile0 = n0; }
            const int row = row0 + lrow;
            const int swc = col8 ^ ((row & 7) << 3);
            gsrc[j] = src + (size_t)(tile0 + row) * K + swc;
            ldst[j] = buf + row0 * 64;
        }
    }

    f32x4 acc[4][2] = {};
    const int sw = (r16 & 7) << 3;

    for (int k0 = 0; k0 < K; k0 += 64) {
        #pragma unroll
        for (int j = 0; j < 12; ++j) gload16(gsrc[j] + k0, ldst[j]);
        __syncthreads();   // drains vmcnt: tiles ready (and prior reads done)

        #pragma unroll
        for (int ks = 0; ks < 2; ++ks) {
            bf16x8 fah[4], fal[4], fbh[2], fbl[2];
            #pragma unroll
            for (int f = 0; f < 4; ++f) {
                const int off = (f * 16 + r16) * 64 + ((ks * 32 + g4 * 8) ^ sw);
                fah[f] = *(const bf16x8*)&sAh[off];
                fal[f] = *(const bf16x8*)&sAl[off];
            }
            #pragma unroll
            for (int f = 0; f < 2; ++f) {
                const int off = (wv * 32 + f * 16 + r16) * 64 + ((ks * 32 + g4 * 8) ^ sw);
                fbh[f] = *(const bf16x8*)&sWh[off];
                fbl[f] = *(const bf16x8*)&sWl[off];
            }
            #pragma unroll
            for (int i = 0; i < 4; ++i)
                #pragma unroll
                for (int j = 0; j < 2; ++j) {
                    acc[i][j] = __builtin_amdgcn_mfma_f32_16x16x32_bf16(
                        fah[i], fbh[j], acc[i][j], 0, 0, 0);
                    acc[i][j] = __builtin_amdgcn_mfma_f32_16x16x32_bf16(
                        fal[i], fbh[j], acc[i][j], 0, 0, 0);
                    acc[i][j] = __builtin_amdgcn_mfma_f32_16x16x32_bf16(
                        fah[i], fbl[j], acc[i][j], 0, 0, 0);
                }
        }
        __syncthreads();   // frag reads done before next overwrite
    }

    // ---- epilogue ----
    #pragma unroll
    for (int i = 0; i < 4; ++i) {
        const int grow = m0 + i * 16 + g4 * 4;
        #pragma unroll
        for (int j = 0; j < 2; ++j) {
            const int gcol = n0 + wv * 32 + j * 16 + r16;
            const float bv = bias ? bias[gcol] : 0.0f;
            #pragma unroll
            for (int r = 0; r < 4; ++r) {
                float v = acc[i][j][r] + bv;
                if (act) v = 0.5f * v * (1.0f + erff(v * 0.70710678118654752f));
                const size_t off = (size_t)(grow + r) * N + gcol;
                if (Ch) {
                    short h_, l_; splitRT(v, h_, l_);
                    Ch[off] = h_; Cl[off] = l_;
                } else {
                    if (resid) v += resid[off];
                    Cf[off] = v;
                }
            }
        }
    }
}

// ----------------------------------------------------------------------------
// MFMA flash attention on pre-split bf16 hi/lo Q/K/V; emits bf16 hi/lo O.
// (unchanged from round 4)
// ----------------------------------------------------------------------------
__global__ __launch_bounds__(256) void attn_mfma(
    const short* __restrict__ Qh_, const short* __restrict__ Ql_,
    const short* __restrict__ Kh_, const short* __restrict__ Kl_,
    const short* __restrict__ Vh_, const short* __restrict__ Vl_,
    short* __restrict__ Oh_, short* __restrict__ Ol_,
    int q_ts, int kv_ts, long long q_bs, long long kv_bs)
{
    __shared__ __attribute__((aligned(16))) short Kth[64 * 64];
    __shared__ __attribute__((aligned(16))) short Ktl[64 * 64];
    __shared__ __attribute__((aligned(16))) short Vth[64 * 64];
    __shared__ __attribute__((aligned(16))) short Vtl[64 * 64];
    __shared__ __attribute__((aligned(16))) short Pth[64 * 64];
    __shared__ __attribute__((aligned(16))) short Ptl[64 * 64];

    const int t    = threadIdx.x;
    const int lane = t & 63;
    const int w    = t >> 6;
    const int r16  = lane & 15;
    const int g4   = lane >> 4;

    int bid = blockIdx.x;
    const int qt = bid & 7;  bid >>= 3;
    const int h  = bid % Hc;
    const int b  = bid / Hc;
    const int q0 = qt * 64;

    const int myq = w * 16 + r16;
    const int qsw = (myq & 7) << 3;

    bf16x8 qh[2], ql[2];
    {
        const short* qrh = Qh_ + (size_t)b * q_bs + (size_t)(q0 + myq) * q_ts + h * HDc;
        const short* qrl = Ql_ + (size_t)b * q_bs + (size_t)(q0 + myq) * q_ts + h * HDc;
        #pragma unroll
        for (int ks = 0; ks < 2; ++ks) {
            qh[ks] = *(const bf16x8*)(qrh + ks * 32 + g4 * 8);
            ql[ks] = *(const bf16x8*)(qrl + ks * 32 + g4 * 8);
        }
    }

    const short* kbh = Kh_ + (size_t)b * kv_bs + h * HDc;
    const short* kbl = Kl_ + (size_t)b * kv_bs + h * HDc;
    const short* vbh = Vh_ + (size_t)b * kv_bs + h * HDc;
    const short* vbl = Vl_ + (size_t)b * kv_bs + h * HDc;

    const int skv = t >> 2,       sd = (t & 3) * 16;
    const int vkv = (t >> 4) * 4, vd = (t & 15) * 4;
    const int ksw = (skv & 7) << 3;
    const float qsc = 0.125f * 1.44269504088896340736f;

    f32x4 oAcc[4] = {};
    float mrun = -3.0e38f;
    float lrun = 0.0f;

    for (int kt = 0; kt < 8; ++kt) {
        __syncthreads();
        {
            const short* kr_h = kbh + (size_t)(kt * 64 + skv) * kv_ts + sd;
            const short* kr_l = kbl + (size_t)(kt * 64 + skv) * kv_ts + sd;
            const int base = skv * 64;
            *(bf16x8*)&Kth[base + (sd ^ ksw)]       = *(const bf16x8*)(kr_h);
            *(bf16x8*)&Kth[base + ((sd + 8) ^ ksw)] = *(const bf16x8*)(kr_h + 8);
            *(bf16x8*)&Ktl[base + (sd ^ ksw)]       = *(const bf16x8*)(kr_l);
            *(bf16x8*)&Ktl[base + ((sd + 8) ^ ksw)] = *(const bf16x8*)(kr_l + 8);
        }
        {
            const short* vr_h = vbh + (size_t)(kt * 64 + vkv) * kv_ts + vd;
            const short* vr_l = vbl + (size_t)(kt * 64 + vkv) * kv_ts + vd;
            short4v h0 = *(const short4v*)(vr_h);
            short4v h1 = *(const short4v*)(vr_h + kv_ts);
            short4v h2 = *(const short4v*)(vr_h + 2 * (size_t)kv_ts);
            short4v h3 = *(const short4v*)(vr_h + 3 * (size_t)kv_ts);
            short4v l0 = *(const short4v*)(vr_l);
            short4v l1 = *(const short4v*)(vr_l + kv_ts);
            short4v l2 = *(const short4v*)(vr_l + 2 * (size_t)kv_ts);
            short4v l3 = *(const short4v*)(vr_l + 3 * (size_t)kv_ts);
            #pragma unroll
            for (int j = 0; j < 4; ++j) {
                const int dd = vd + j;
                short4v hv, lv;
                hv[0] = h0[j]; hv[1] = h1[j]; hv[2] = h2[j]; hv[3] = h3[j];
                lv[0] = l0[j]; lv[1] = l1[j]; lv[2] = l2[j]; lv[3] = l3[j];
                const int off = dd * 64 + (vkv ^ ((dd & 7) << 3));
                *(short4v*)&Vth[off] = hv;
                *(short4v*)&Vtl[off] = lv;
            }
        }
        __syncthreads();

        f32x4 s4[4] = {};
        #pragma unroll
        for (int st = 0; st < 4; ++st) {
            const int kvl = st * 16 + r16;
            const int ssw = (kvl & 7) << 3;
            #pragma unroll
            for (int ks = 0; ks < 2; ++ks) {
                const int off = kvl * 64 + ((ks * 32 + g4 * 8) ^ ssw);
                const bf16x8 kh = *(const bf16x8*)&Kth[off];
                const bf16x8 kl = *(const bf16x8*)&Ktl[off];
                s4[st] = __builtin_amdgcn_mfma_f32_16x16x32_bf16(kh, qh[ks], s4[st], 0, 0, 0);
                s4[st] = __builtin_amdgcn_mfma_f32_16x16x32_bf16(kl, qh[ks], s4[st], 0, 0, 0);
                s4[st] = __builtin_amdgcn_mfma_f32_16x16x32_bf16(kh, ql[ks], s4[st], 0, 0, 0);
            }
        }
        #pragma unroll
        for (int st = 0; st < 4; ++st)
            #pragma unroll
            for (int r = 0; r < 4; ++r) s4[st][r] *= qsc;

        float tmax = -3.0e38f;
        #pragma unroll
        for (int st = 0; st < 4; ++st)
            #pragma unroll
            for (int r = 0; r < 4; ++r) tmax = fmaxf(tmax, s4[st][r]);
        tmax = fmaxf(tmax, __shfl_xor(tmax, 16));
        tmax = fmaxf(tmax, __shfl_xor(tmax, 32));
        const float mnew = fmaxf(mrun, tmax);
        const float fscale = exp2f(mrun - mnew);
        float psum = 0.0f;
        #pragma unroll
        for (int st = 0; st < 4; ++st)
            #pragma unroll
            for (int r = 0; r < 4; ++r) {
                const float e = exp2f(s4[st][r] - mnew);
                s4[st][r] = e;
                psum += e;
            }
        psum += __shfl_xor(psum, 16);
        psum += __shfl_xor(psum, 32);
        lrun = lrun * fscale + psum;
        mrun = mnew;
        #pragma unroll
        for (int dt = 0; dt < 4; ++dt) oAcc[dt] *= fscale;

        #pragma unroll
        for (int st = 0; st < 4; ++st) {
            short4v ph, pl;
            #pragma unroll
            for (int r = 0; r < 4; ++r) {
                const short hi = bhi(s4[st][r]);
                ph[r] = hi;
                pl[r] = bhi(bresid(s4[st][r], hi));
            }
            const int off = myq * 64 + ((st * 16 + g4 * 4) ^ qsw);
            *(short4v*)&Pth[off] = ph;
            *(short4v*)&Ptl[off] = pl;
        }

        #pragma unroll
        for (int ks = 0; ks < 2; ++ks) {
            const int poff = myq * 64 + ((ks * 32 + g4 * 8) ^ qsw);
            const bf16x8 pf_h = *(const bf16x8*)&Pth[poff];
            const bf16x8 pf_l = *(const bf16x8*)&Ptl[poff];
            #pragma unroll
            for (int dt = 0; dt < 4; ++dt) {
                const int dd = dt * 16 + r16;
                const int voff = dd * 64 + ((ks * 32 + g4 * 8) ^ ((dd & 7) << 3));
                const bf16x8 vh = *(const bf16x8*)&Vth[voff];
                const bf16x8 vl = *(const bf16x8*)&Vtl[voff];
                oAcc[dt] = __builtin_amdgcn_mfma_f32_16x16x32_bf16(vh, pf_h, oAcc[dt], 0, 0, 0);
                oAcc[dt] = __builtin_amdgcn_mfma_f32_16x16x32_bf16(vl, pf_h, oAcc[dt], 0, 0, 0);
                oAcc[dt] = __builtin_amdgcn_mfma_f32_16x16x32_bf16(vh, pf_l, oAcc[dt], 0, 0, 0);
            }
        }
    }

    const float inv = 1.0f / lrun;
    short* orh = Oh_ + (size_t)(b * LQc + q0 + myq) * Dc + h * HDc;
    short* orl = Ol_ + (size_t)(b * LQc + q0 + myq) * Dc + h * HDc;
    #pragma unroll
    for (int dt = 0; dt < 4; ++dt) {
        short4v hv, lv;
        #pragma unroll
        for (int r = 0; r < 4; ++r) {
            short h_, l_;
            splitRT(oAcc[dt][r] * inv, h_, l_);
            hv[r] = h_; lv[r] = l_;
        }
        *(short4v*)&orh[dt * 16 + g4 * 4] = hv;
        *(short4v*)&orl[dt * 16 + g4 * 4] = lv;
    }
}

} // anonymous namespace

// ----------------------------------------------------------------------------
// Launcher
// ----------------------------------------------------------------------------
extern "C" void kernel_launch(void* const* d_in, const int* in_sizes, int n_in,
                              void* d_out, int out_size, void* d_ws, size_t ws_size,
                              hipStream_t stream)
{
    const float* q_in   = (const float*)d_in[0];
    const float* kv_in  = (const float*)d_in[1];
    const float* n1g    = (const float*)d_in[2];
    const float* n1b    = (const float*)d_in[3];
    const float* qkv_w  = (const float*)d_in[4];
    const float* sa_w   = (const float*)d_in[5];
    const float* sa_b   = (const float*)d_in[6];
    const float* n2qg   = (const float*)d_in[7];
    const float* n2qb   = (const float*)d_in[8];
    const float* n2kg   = (const float*)d_in[9];
    const float* n2kb   = (const float*)d_in[10];
    const float* caq_w  = (const float*)d_in[11];
    const float* cakv_w = (const float*)d_in[12];
    const float* cap_w  = (const float*)d_in[13];
    const float* cap_b  = (const float*)d_in[14];
    const float* n3g    = (const float*)d_in[15];
    const float* n3b    = (const float*)d_in[16];
    const float* fc1_w  = (const float*)d_in[17];
    const float* fc1_b  = (const float*)d_in[18];
    const float* fc2_w  = (const float*)d_in[19];
    const float* fc2_b  = (const float*)d_in[20];
    float* out = (float*)d_out;

    const size_t MQ = (size_t)Bc * LQc * Dc;         // 6,291,456 elems

    const int wqkv = 3 * Dc * Dc, wsa = Dc * Dc, wcaq = Dc * Dc,
              wcakv = 2 * Dc * Dc, wcap = Dc * Dc,
              wfc1 = HIDc * Dc, wfc2 = Dc * HIDc;

    short* wsS = (short*)d_ws;
    size_t off = 0;
    auto alloc = [&](size_t n) { short* p = wsS + off; off += n; return p; };

    short* WqkvH  = alloc(wqkv);  short* WqkvL  = alloc(wqkv);
    short* WsaH   = alloc(wsa);   short* WsaL   = alloc(wsa);
    short* WcaqH  = alloc(wcaq);  short* WcaqL  = alloc(wcaq);
    short* WcakvH = alloc(wcakv); short* WcakvL = alloc(wcakv);
    short* WcapH  = alloc(wcap);  short* WcapL  = alloc(wcap);
    short* Wfc1H  = alloc(wfc1);  short* Wfc1L  = alloc(wfc1);
    short* Wfc2H  = alloc(wfc2);  short* Wfc2L  = alloc(wfc2);
    short* P1H    = alloc(MQ);    short* P1L    = alloc(MQ);
    short* bigH   = alloc(4 * MQ);
    short* bigL   = alloc(4 * MQ);
    short* xkvH = bigH + 2 * MQ;  short* xkvL = bigL + 2 * MQ;
    short* qcH  = bigH + 3 * MQ;  short* qcL  = bigL + 3 * MQ;

    const int ROWS = Bc * LQc;            // 8192
    const dim3 blk(256);
    const dim3 lnGrid(ROWS);
    const dim3 attnGrid(Bc * Hc * (LQc / 64));   // 1536

    // 0. split all weights once
    {
        SplitArgs a;
        const float* srcs[7] = {qkv_w, sa_w, caq_w, cakv_w, cap_w, fc1_w, fc2_w};
        short* dhs[7] = {WqkvH, WsaH, WcaqH, WcakvH, WcapH, Wfc1H, Wfc2H};
        short* dls[7] = {WqkvL, WsaL, WcaqL, WcakvL, WcapL, Wfc1L, Wfc2L};
        const int ns[7] = {wqkv, wsa, wcaq, wcakv, wcap, wfc1, wfc2};
        int c = 0;
        for (int i = 0; i < 7; ++i) {
            a.src[i] = srcs[i]; a.dh[i] = dhs[i]; a.dl[i] = dls[i];
            a.cum4[i] = c; c += ns[i] / 4;
        }
        a.cum4[7] = c;
        split_w<<<dim3(1024), blk, 0, stream>>>(a);
    }

    auto gemm = [&](const short* Ah, const short* Al, const short* Wh, const short* Wl,
                    const float* bias, const float* resid,
                    float* Cf, short* Ch, short* Cl, int N, int K, int act) {
        const int gx = N / 128;
        gemm_bf3<<<dim3(gx, ROWS / 64), blk, 0, stream>>>(
            Ah, Al, Wh, Wl, bias, resid, Cf, Ch, Cl, N, K, act, gx);
    };

    // 1. x1 = LN1(q) -> P1
    ln_kernel<<<lnGrid, blk, 0, stream>>>(q_in, n1g, n1b, P1H, P1L);
    // 2. qkv = x1 @ qkv_w^T -> big pair [0,3MQ)
    gemm(P1H, P1L, WqkvH, WqkvL, nullptr, nullptr, nullptr, bigH, bigL, 3 * Dc, Dc, 0);
    // 3. sa_out = attend(q,k,v) -> P1
    attn_mfma<<<attnGrid, blk, 0, stream>>>(
        bigH, bigL, bigH + Dc, bigL + Dc, bigH + 2 * Dc, bigL + 2 * Dc,
        P1H, P1L, 3 * Dc, 3 * Dc, (long long)LQc * 3 * Dc, (long long)LKVc * 3 * Dc);
    // 4. q1 = sa_out @ sa_w^T + sa_b + q -> out (fp32)
    gemm(P1H, P1L, WsaH, WsaL, sa_b, q_in, out, nullptr, nullptr, Dc, Dc, 0);
    // 5. xq = LN2q(q1) -> P1
    ln_kernel<<<lnGrid, blk, 0, stream>>>(out, n2qg, n2qb, P1H, P1L);
    // 6. xkv = LN2kv(kv) -> big[2MQ,3MQ)
    ln_kernel<<<lnGrid, blk, 0, stream>>>(kv_in, n2kg, n2kb, xkvH, xkvL);
    // 7. qc = xq @ caq_w^T -> big[3MQ,4MQ)
    gemm(P1H, P1L, WcaqH, WcaqL, nullptr, nullptr, nullptr, qcH, qcL, Dc, Dc, 0);
    // 8. kvc = xkv @ cakv_w^T -> big[0,2MQ)
    gemm(xkvH, xkvL, WcakvH, WcakvL, nullptr, nullptr, nullptr, bigH, bigL, 2 * Dc, Dc, 0);
    // 9. ca_out = attend(qc, kc, vc) -> P1
    attn_mfma<<<attnGrid, blk, 0, stream>>>(
        qcH, qcL, bigH, bigL, bigH + Dc, bigL + Dc,
        P1H, P1L, Dc, 2 * Dc, (long long)LQc * Dc, (long long)LKVc * 2 * Dc);
    // 10. q2 = ca_out @ cap_w^T + cap_b + q1 -> out
    gemm(P1H, P1L, WcapH, WcapL, cap_b, out, out, nullptr, nullptr, Dc, Dc, 0);
    // 11. x3 = LN3(q2) -> P1
    ln_kernel<<<lnGrid, blk, 0, stream>>>(out, n3g, n3b, P1H, P1L);
    // 12. hidden = gelu(x3 @ fc1^T + fc1_b) -> big pair [0,4MQ)
    gemm(P1H, P1L, Wfc1H, Wfc1L, fc1_b, nullptr, nullptr, bigH, bigL, HIDc, Dc, 1);
    // 13. out = hidden @ fc2^T + fc2_b + q2 -> out
    gemm(bigH, bigL, Wfc2H, Wfc2L, fc2_b, out, out, nullptr, nullptr, Dc, HIDc, 0);
}

// Round 7
// 800.035 us; speedup vs baseline: 4.7388x; 1.1620x over previous
//
#include <hip/hip_runtime.h>

namespace {

constexpr int Bc   = 16;
constexpr int LQc  = 512;
constexpr int LKVc = 512;
constexpr int Dc   = 768;
constexpr int Hc   = 12;
constexpr int HDc  = 64;
constexpr int HIDc = 3072;

using bf16x8  = __attribute__((ext_vector_type(8))) short;
using short4v = __attribute__((ext_vector_type(4))) short;
using f32x4   = __attribute__((ext_vector_type(4))) float;

__device__ inline short f2bf(float x) {              // round-to-nearest-even
    union { float f; unsigned u; } v; v.f = x;
    const unsigned r = v.u + 0x7fffu + ((v.u >> 16) & 1u);
    return (short)(r >> 16);
}
__device__ inline float bf2f(short h) {
    union { unsigned u; float f; } v;
    v.u = ((unsigned)(unsigned short)h) << 16;
    return v.f;
}
__device__ inline void splitRT(float x, short& h, short& l) {
    h = f2bf(x);
    l = f2bf(x - bf2f(h));
}
__device__ inline void gload16(const void* g, void* lds) {
    __builtin_amdgcn_global_load_lds(
        (const __attribute__((address_space(1))) unsigned int*)g,
        (__attribute__((address_space(3))) unsigned int*)lds, 16, 0, 0);
}

// ----------------------------------------------------------------------------
// Weight pre-round: fp32 -> bf16 (RNE), 7 tensors in one launch.
// ----------------------------------------------------------------------------
struct SplitArgs {
    const float* src[7];
    short* dh[7];
    int cum4[8];     // cumulative float4 counts
};

__global__ __launch_bounds__(256) void split_w(SplitArgs a) {
    const int total = a.cum4[7];
    for (int i = blockIdx.x * 256 + threadIdx.x; i < total; i += gridDim.x * 256) {
        int s = 0;
        while (i >= a.cum4[s + 1]) ++s;
        const int off = i - a.cum4[s];
        const f32x4 v = *((const f32x4*)a.src[s] + off);
        short4v h;
        #pragma unroll
        for (int j = 0; j < 4; ++j) h[j] = f2bf(v[j]);
        *((short4v*)a.dh[s] + off) = h;
    }
}

// ----------------------------------------------------------------------------
// LayerNorm: one block per row; emits bf16 hi/lo pair.
// ----------------------------------------------------------------------------
__global__ __launch_bounds__(256) void ln_kernel(
    const float* __restrict__ X, const float* __restrict__ g,
    const float* __restrict__ bta, short* __restrict__ Yh, short* __restrict__ Yl)
{
    const int row = blockIdx.x;
    const float* x = X + (size_t)row * Dc;
    const int t = threadIdx.x;
    const float v0 = x[t], v1 = x[t + 256], v2 = x[t + 512];
    float s  = v0 + v1 + v2;
    float ss = v0 * v0 + v1 * v1 + v2 * v2;
    #pragma unroll
    for (int off = 32; off > 0; off >>= 1) {
        s  += __shfl_down(s, off);
        ss += __shfl_down(ss, off);
    }
    __shared__ float red[8];
    __shared__ float mv[2];
    const int wid = t >> 6;
    if ((t & 63) == 0) { red[wid] = s; red[wid + 4] = ss; }
    __syncthreads();
    if (t == 0) {
        const float S  = red[0] + red[1] + red[2] + red[3];
        const float SS = red[4] + red[5] + red[6] + red[7];
        const float mean = S * (1.0f / Dc);
        const float var  = SS * (1.0f / Dc) - mean * mean;
        mv[0] = mean;
        mv[1] = rsqrtf(var + 1e-5f);
    }
    __syncthreads();
    const float mean = mv[0], inv = mv[1];
    short h0, l0, h1, l1, h2, l2;
    splitRT((v0 - mean) * inv * g[t]       + bta[t],       h0, l0);
    splitRT((v1 - mean) * inv * g[t + 256] + bta[t + 256], h1, l1);
    splitRT((v2 - mean) * inv * g[t + 512] + bta[t + 512], h2, l2);
    const size_t rb = (size_t)row * Dc;
    Yh[rb + t] = h0;        Yl[rb + t] = l0;
    Yh[rb + t + 256] = h1;  Yl[rb + t + 256] = l1;
    Yh[rb + t + 512] = h2;  Yl[rb + t + 512] = l2;
}

// ----------------------------------------------------------------------------
// Unified MFMA GEMM (NT), 2-term: C = (Ah+Al) @ Wh^T. Tile 64x128, BK=64,
// 256 threads (4 waves, each 64x32). LDS 32KB -> 4-5 blocks/CU.
// global_load_lds with pre-swizzled global source (LDS linear, reads XOR'd).
// XCD-chunked N-major block remap. fp32 accumulate.
// ----------------------------------------------------------------------------
__global__ __launch_bounds__(256, 4) void gemm_bf2(
    const short* __restrict__ Ahp, const short* __restrict__ Alp,
    const short* __restrict__ Whp,
    const float* __restrict__ bias, const float* __restrict__ resid,
    float* __restrict__ Cf, short* __restrict__ Ch, short* __restrict__ Cl,
    int N, int K, int act, int gx)
{
    __shared__ __attribute__((aligned(16))) short sAh[64 * 64];
    __shared__ __attribute__((aligned(16))) short sAl[64 * 64];
    __shared__ __attribute__((aligned(16))) short sWh[128 * 64];

    const int t    = threadIdx.x;
    const int lane = t & 63;
    const int wv   = t >> 6;
    const int r16  = lane & 15;
    const int g4   = lane >> 4;

    // XCD-chunked, N-major remap (bijective: nwg = gx*128, %8==0)
    const int flat = blockIdx.x + gx * blockIdx.y;
    const int l    = (flat & 7) * (gx << 4) + (flat >> 3);
    const int by   = l & 127;          // M-block (fast within chunk)
    const int bx   = l >> 7;           // N-block
    const int m0   = by << 6;
    const int n0   = bx << 7;

    // ---- staging setup: 32 chunks of 1KB (8 rows x 64 shorts); 8 per wave ----
    const short* gsrc[8];
    short* ldst[8];
    {
        const int lrow = lane >> 3;
        const int col8 = (lane & 7) << 3;
        #pragma unroll
        for (int j = 0; j < 8; ++j) {
            const int c = wv * 8 + j;
            const short* src; short* buf; int row0, tile0;
            if (c < 8)       { src = Ahp; buf = sAh; row0 = c * 8;        tile0 = m0; }
            else if (c < 16) { src = Alp; buf = sAl; row0 = (c - 8) * 8;  tile0 = m0; }
            else             { src = Whp; buf = sWh; row0 = (c - 16) * 8; tile0 = n0; }
            const int row = row0 + lrow;
            const int swc = col8 ^ ((row & 7) << 3);
            gsrc[j] = src + (size_t)(tile0 + row) * K + swc;
            ldst[j] = buf + row0 * 64;
        }
    }

    f32x4 acc[4][2] = {};
    const int sw = (r16 & 7) << 3;

    for (int k0 = 0; k0 < K; k0 += 64) {
        #pragma unroll
        for (int j = 0; j < 8; ++j) gload16(gsrc[j] + k0, ldst[j]);
        __syncthreads();   // drains vmcnt: tiles ready (and prior reads done)

        #pragma unroll
        for (int ks = 0; ks < 2; ++ks) {
            bf16x8 fah[4], fal[4], fbh[2];
            #pragma unroll
            for (int f = 0; f < 4; ++f) {
                const int off = (f * 16 + r16) * 64 + ((ks * 32 + g4 * 8) ^ sw);
                fah[f] = *(const bf16x8*)&sAh[off];
                fal[f] = *(const bf16x8*)&sAl[off];
            }
            #pragma unroll
            for (int f = 0; f < 2; ++f) {
                const int off = (wv * 32 + f * 16 + r16) * 64 + ((ks * 32 + g4 * 8) ^ sw);
                fbh[f] = *(const bf16x8*)&sWh[off];
            }
            #pragma unroll
            for (int i = 0; i < 4; ++i)
                #pragma unroll
                for (int j = 0; j < 2; ++j) {
                    acc[i][j] = __builtin_amdgcn_mfma_f32_16x16x32_bf16(
                        fah[i], fbh[j], acc[i][j], 0, 0, 0);
                    acc[i][j] = __builtin_amdgcn_mfma_f32_16x16x32_bf16(
                        fal[i], fbh[j], acc[i][j], 0, 0, 0);
                }
        }
        __syncthreads();   // frag reads done before next overwrite
    }

    // ---- epilogue ----
    #pragma unroll
    for (int i = 0; i < 4; ++i) {
        const int grow = m0 + i * 16 + g4 * 4;
        #pragma unroll
        for (int j = 0; j < 2; ++j) {
            const int gcol = n0 + wv * 32 + j * 16 + r16;
            const float bv = bias ? bias[gcol] : 0.0f;
            #pragma unroll
            for (int r = 0; r < 4; ++r) {
                float v = acc[i][j][r] + bv;
                if (act) v = 0.5f * v * (1.0f + erff(v * 0.70710678118654752f));
                const size_t off = (size_t)(grow + r) * N + gcol;
                if (Ch) {
                    short h_, l_; splitRT(v, h_, l_);
                    Ch[off] = h_; Cl[off] = l_;
                } else {
                    if (resid) v += resid[off];
                    Cf[off] = v;
                }
            }
        }
    }
}

// ----------------------------------------------------------------------------
// MFMA flash attention, 2-term: S = (Kh+Kl)·Qh ; O += (Vh+Vl)·Ph.
// Block = 256 thr (4 waves), 64 q rows. Swapped QK^T, online softmax,
// XOR-swizzled LDS. P single-bf16 (RNE).
// ----------------------------------------------------------------------------
__global__ __launch_bounds__(256) void attn_mfma(
    const short* __restrict__ Qh_,
    const short* __restrict__ Kh_, const short* __restrict__ Kl_,
    const short* __restrict__ Vh_, const short* __restrict__ Vl_,
    short* __restrict__ Oh_, short* __restrict__ Ol_,
    int q_ts, int kv_ts, long long q_bs, long long kv_bs)
{
    __shared__ __attribute__((aligned(16))) short Kth[64 * 64];
    __shared__ __attribute__((aligned(16))) short Ktl[64 * 64];
    __shared__ __attribute__((aligned(16))) short Vth[64 * 64];
    __shared__ __attribute__((aligned(16))) short Vtl[64 * 64];
    __shared__ __attribute__((aligned(16))) short Pth[64 * 64];

    const int t    = threadIdx.x;
    const int lane = t & 63;
    const int w    = t >> 6;
    const int r16  = lane & 15;
    const int g4   = lane >> 4;

    int bid = blockIdx.x;
    const int qt = bid & 7;  bid >>= 3;
    const int h  = bid % Hc;
    const int b  = bid / Hc;
    const int q0 = qt * 64;

    const int myq = w * 16 + r16;
    const int qsw = (myq & 7) << 3;

    bf16x8 qh[2];
    {
        const short* qrh = Qh_ + (size_t)b * q_bs + (size_t)(q0 + myq) * q_ts + h * HDc;
        #pragma unroll
        for (int ks = 0; ks < 2; ++ks)
            qh[ks] = *(const bf16x8*)(qrh + ks * 32 + g4 * 8);
    }

    const short* kbh = Kh_ + (size_t)b * kv_bs + h * HDc;
    const short* kbl = Kl_ + (size_t)b * kv_bs + h * HDc;
    const short* vbh = Vh_ + (size_t)b * kv_bs + h * HDc;
    const short* vbl = Vl_ + (size_t)b * kv_bs + h * HDc;

    const int skv = t >> 2,       sd = (t & 3) * 16;
    const int vkv = (t >> 4) * 4, vd = (t & 15) * 4;
    const int ksw = (skv & 7) << 3;
    const float qsc = 0.125f * 1.44269504088896340736f;   // hd^-0.5 * log2(e)

    f32x4 oAcc[4] = {};
    float mrun = -3.0e38f;
    float lrun = 0.0f;

    for (int kt = 0; kt < 8; ++kt) {
        __syncthreads();
        {
            const short* kr_h = kbh + (size_t)(kt * 64 + skv) * kv_ts + sd;
            const short* kr_l = kbl + (size_t)(kt * 64 + skv) * kv_ts + sd;
            const int base = skv * 64;
            *(bf16x8*)&Kth[base + (sd ^ ksw)]       = *(const bf16x8*)(kr_h);
            *(bf16x8*)&Kth[base + ((sd + 8) ^ ksw)] = *(const bf16x8*)(kr_h + 8);
            *(bf16x8*)&Ktl[base + (sd ^ ksw)]       = *(const bf16x8*)(kr_l);
            *(bf16x8*)&Ktl[base + ((sd + 8) ^ ksw)] = *(const bf16x8*)(kr_l + 8);
        }
        {
            const short* vr_h = vbh + (size_t)(kt * 64 + vkv) * kv_ts + vd;
            const short* vr_l = vbl + (size_t)(kt * 64 + vkv) * kv_ts + vd;
            short4v h0 = *(const short4v*)(vr_h);
            short4v h1 = *(const short4v*)(vr_h + kv_ts);
            short4v h2 = *(const short4v*)(vr_h + 2 * (size_t)kv_ts);
            short4v h3 = *(const short4v*)(vr_h + 3 * (size_t)kv_ts);
            short4v l0 = *(const short4v*)(vr_l);
            short4v l1 = *(const short4v*)(vr_l + kv_ts);
            short4v l2 = *(const short4v*)(vr_l + 2 * (size_t)kv_ts);
            short4v l3 = *(const short4v*)(vr_l + 3 * (size_t)kv_ts);
            #pragma unroll
            for (int j = 0; j < 4; ++j) {
                const int dd = vd + j;
                short4v hv, lv;
                hv[0] = h0[j]; hv[1] = h1[j]; hv[2] = h2[j]; hv[3] = h3[j];
                lv[0] = l0[j]; lv[1] = l1[j]; lv[2] = l2[j]; lv[3] = l3[j];
                const int off = dd * 64 + (vkv ^ ((dd & 7) << 3));
                *(short4v*)&Vth[off] = hv;
                *(short4v*)&Vtl[off] = lv;
            }
        }
        __syncthreads();

        // ---- swapped QK^T: S^T[kv][q], 2-term (K exact, Q bf16) ----
        f32x4 s4[4] = {};
        #pragma unroll
        for (int st = 0; st < 4; ++st) {
            const int kvl = st * 16 + r16;
            const int ssw = (kvl & 7) << 3;
            #pragma unroll
            for (int ks = 0; ks < 2; ++ks) {
                const int off = kvl * 64 + ((ks * 32 + g4 * 8) ^ ssw);
                const bf16x8 kh = *(const bf16x8*)&Kth[off];
                const bf16x8 kl = *(const bf16x8*)&Ktl[off];
                s4[st] = __builtin_amdgcn_mfma_f32_16x16x32_bf16(kh, qh[ks], s4[st], 0, 0, 0);
                s4[st] = __builtin_amdgcn_mfma_f32_16x16x32_bf16(kl, qh[ks], s4[st], 0, 0, 0);
            }
        }
        #pragma unroll
        for (int st = 0; st < 4; ++st)
            #pragma unroll
            for (int r = 0; r < 4; ++r) s4[st][r] *= qsc;

        // ---- online softmax ----
        float tmax = -3.0e38f;
        #pragma unroll
        for (int st = 0; st < 4; ++st)
            #pragma unroll
            for (int r = 0; r < 4; ++r) tmax = fmaxf(tmax, s4[st][r]);
        tmax = fmaxf(tmax, __shfl_xor(tmax, 16));
        tmax = fmaxf(tmax, __shfl_xor(tmax, 32));
        const float mnew = fmaxf(mrun, tmax);
        const float fscale = exp2f(mrun - mnew);
        float psum = 0.0f;
        #pragma unroll
        for (int st = 0; st < 4; ++st)
            #pragma unroll
            for (int r = 0; r < 4; ++r) {
                const float e = exp2f(s4[st][r] - mnew);
                s4[st][r] = e;
                psum += e;
            }
        psum += __shfl_xor(psum, 16);
        psum += __shfl_xor(psum, 32);
        lrun = lrun * fscale + psum;
        mrun = mnew;
        #pragma unroll
        for (int dt = 0; dt < 4; ++dt) oAcc[dt] *= fscale;

        // ---- write P tile (single bf16, RNE) ----
        #pragma unroll
        for (int st = 0; st < 4; ++st) {
            short4v ph;
            #pragma unroll
            for (int r = 0; r < 4; ++r) ph[r] = f2bf(s4[st][r]);
            const int off = myq * 64 + ((st * 16 + g4 * 4) ^ qsw);
            *(short4v*)&Pth[off] = ph;
        }

        // ---- PV: O^T[d][q] += (Vh+Vl) * P ----
        #pragma unroll
        for (int ks = 0; ks < 2; ++ks) {
            const int poff = myq * 64 + ((ks * 32 + g4 * 8) ^ qsw);
            const bf16x8 pf = *(const bf16x8*)&Pth[poff];
            #pragma unroll
            for (int dt = 0; dt < 4; ++dt) {
                const int dd = dt * 16 + r16;
                const int voff = dd * 64 + ((ks * 32 + g4 * 8) ^ ((dd & 7) << 3));
                const bf16x8 vh = *(const bf16x8*)&Vth[voff];
                const bf16x8 vl = *(const bf16x8*)&Vtl[voff];
                oAcc[dt] = __builtin_amdgcn_mfma_f32_16x16x32_bf16(vh, pf, oAcc[dt], 0, 0, 0);
                oAcc[dt] = __builtin_amdgcn_mfma_f32_16x16x32_bf16(vl, pf, oAcc[dt], 0, 0, 0);
            }
        }
    }

    const float inv = 1.0f / lrun;
    short* orh = Oh_ + (size_t)(b * LQc + q0 + myq) * Dc + h * HDc;
    short* orl = Ol_ + (size_t)(b * LQc + q0 + myq) * Dc + h * HDc;
    #pragma unroll
    for (int dt = 0; dt < 4; ++dt) {
        short4v hv, lv;
        #pragma unroll
        for (int r = 0; r < 4; ++r) {
            short h_, l_;
            splitRT(oAcc[dt][r] * inv, h_, l_);
            hv[r] = h_; lv[r] = l_;
        }
        *(short4v*)&orh[dt * 16 + g4 * 4] = hv;
        *(short4v*)&orl[dt * 16 + g4 * 4] = lv;
    }
}

} // anonymous namespace

// ----------------------------------------------------------------------------
// Launcher
// ----------------------------------------------------------------------------
extern "C" void kernel_launch(void* const* d_in, const int* in_sizes, int n_in,
                              void* d_out, int out_size, void* d_ws, size_t ws_size,
                              hipStream_t stream)
{
    const float* q_in   = (const float*)d_in[0];
    const float* kv_in  = (const float*)d_in[1];
    const float* n1g    = (const float*)d_in[2];
    const float* n1b    = (const float*)d_in[3];
    const float* qkv_w  = (const float*)d_in[4];
    const float* sa_w   = (const float*)d_in[5];
    const float* sa_b   = (const float*)d_in[6];
    const float* n2qg   = (const float*)d_in[7];
    const float* n2qb   = (const float*)d_in[8];
    const float* n2kg   = (const float*)d_in[9];
    const float* n2kb   = (const float*)d_in[10];
    const float* caq_w  = (const float*)d_in[11];
    const float* cakv_w = (const float*)d_in[12];
    const float* cap_w  = (const float*)d_in[13];
    const float* cap_b  = (const float*)d_in[14];
    const float* n3g    = (const float*)d_in[15];
    const float* n3b    = (const float*)d_in[16];
    const float* fc1_w  = (const float*)d_in[17];
    const float* fc1_b  = (const float*)d_in[18];
    const float* fc2_w  = (const float*)d_in[19];
    const float* fc2_b  = (const float*)d_in[20];
    float* out = (float*)d_out;

    const size_t MQ = (size_t)Bc * LQc * Dc;         // 6,291,456 elems

    const int wqkv = 3 * Dc * Dc, wsa = Dc * Dc, wcaq = Dc * Dc,
              wcakv = 2 * Dc * Dc, wcap = Dc * Dc,
              wfc1 = HIDc * Dc, wfc2 = Dc * HIDc;

    short* wsS = (short*)d_ws;
    size_t off = 0;
    auto alloc = [&](size_t n) { short* p = wsS + off; off += n; return p; };

    short* WqkvH  = alloc(wqkv);
    short* WsaH   = alloc(wsa);
    short* WcaqH  = alloc(wcaq);
    short* WcakvH = alloc(wcakv);
    short* WcapH  = alloc(wcap);
    short* Wfc1H  = alloc(wfc1);
    short* Wfc2H  = alloc(wfc2);
    short* P1H    = alloc(MQ);    short* P1L    = alloc(MQ);
    short* bigH   = alloc(4 * MQ);
    short* bigL   = alloc(4 * MQ);
    short* xkvH = bigH + 2 * MQ;  short* xkvL = bigL + 2 * MQ;
    short* qcH  = bigH + 3 * MQ;  short* qcL  = bigL + 3 * MQ;

    const int ROWS = Bc * LQc;            // 8192
    const dim3 blk(256);
    const dim3 lnGrid(ROWS);
    const dim3 attnGrid(Bc * Hc * (LQc / 64));   // 1536

    // 0. round all weights to bf16 once
    {
        SplitArgs a;
        const float* srcs[7] = {qkv_w, sa_w, caq_w, cakv_w, cap_w, fc1_w, fc2_w};
        short* dhs[7] = {WqkvH, WsaH, WcaqH, WcakvH, WcapH, Wfc1H, Wfc2H};
        const int ns[7] = {wqkv, wsa, wcaq, wcakv, wcap, wfc1, wfc2};
        int c = 0;
        for (int i = 0; i < 7; ++i) {
            a.src[i] = srcs[i]; a.dh[i] = dhs[i];
            a.cum4[i] = c; c += ns[i] / 4;
        }
        a.cum4[7] = c;
        split_w<<<dim3(1024), blk, 0, stream>>>(a);
    }

    auto gemm = [&](const short* Ah, const short* Al, const short* Wh,
                    const float* bias, const float* resid,
                    float* Cf, short* Ch, short* Cl, int N, int K, int act) {
        const int gx = N / 128;
        gemm_bf2<<<dim3(gx, ROWS / 64), blk, 0, stream>>>(
            Ah, Al, Wh, bias, resid, Cf, Ch, Cl, N, K, act, gx);
    };

    // 1. x1 = LN1(q) -> P1
    ln_kernel<<<lnGrid, blk, 0, stream>>>(q_in, n1g, n1b, P1H, P1L);
    // 2. qkv = x1 @ qkv_w^T -> big pair [0,3MQ)
    gemm(P1H, P1L, WqkvH, nullptr, nullptr, nullptr, bigH, bigL, 3 * Dc, Dc, 0);
    // 3. sa_out = attend(q,k,v) -> P1
    attn_mfma<<<attnGrid, blk, 0, stream>>>(
        bigH, bigH + Dc, bigL + Dc, bigH + 2 * Dc, bigL + 2 * Dc,
        P1H, P1L, 3 * Dc, 3 * Dc, (long long)LQc * 3 * Dc, (long long)LKVc * 3 * Dc);
    // 4. q1 = sa_out @ sa_w^T + sa_b + q -> out (fp32)
    gemm(P1H, P1L, WsaH, sa_b, q_in, out, nullptr, nullptr, Dc, Dc, 0);
    // 5. xq = LN2q(q1) -> P1
    ln_kernel<<<lnGrid, blk, 0, stream>>>(out, n2qg, n2qb, P1H, P1L);
    // 6. xkv = LN2kv(kv) -> big[2MQ,3MQ)
    ln_kernel<<<lnGrid, blk, 0, stream>>>(kv_in, n2kg, n2kb, xkvH, xkvL);
    // 7. qc = xq @ caq_w^T -> big[3MQ,4MQ)
    gemm(P1H, P1L, WcaqH, nullptr, nullptr, nullptr, qcH, qcL, Dc, Dc, 0);
    // 8. kvc = xkv @ cakv_w^T -> big[0,2MQ)
    gemm(xkvH, xkvL, WcakvH, nullptr, nullptr, nullptr, bigH, bigL, 2 * Dc, Dc, 0);
    // 9. ca_out = attend(qc, kc, vc) -> P1
    attn_mfma<<<attnGrid, blk, 0, stream>>>(
        qcH, bigH, bigL, bigH + Dc, bigL + Dc,
        P1H, P1L, Dc, 2 * Dc, (long long)LQc * Dc, (long long)LKVc * 2 * Dc);
    // 10. q2 = ca_out @ cap_w^T + cap_b + q1 -> out
    gemm(P1H, P1L, WcapH, cap_b, out, out, nullptr, nullptr, Dc, Dc, 0);
    // 11. x3 = LN3(q2) -> P1
    ln_kernel<<<lnGrid, blk, 0, stream>>>(out, n3g, n3b, P1H, P1L);
    // 12. hidden = gelu(x3 @ fc1^T + fc1_b) -> big pair [0,4MQ)
    gemm(P1H, P1L, Wfc1H, fc1_b, nullptr, nullptr, bigH, bigL, HIDc, Dc, 1);
    // 13. out = hidden @ fc2^T + fc2_b + q2 -> out
    gemm(bigH, bigL, Wfc2H, fc2_b, out, out, nullptr, nullptr, Dc, HIDc, 0);
}